// Round 3
// baseline (554.302 us; speedup 1.0000x reference)
//
#include <hip/hip_runtime.h>
#include <hip/hip_bf16.h>

#define BB   2
#define SS   2048
#define HH   2048
#define NHH  16
#define QLL  1536
#define KVLL 512
#define NOPE_D 128
#define ROPE_D 64
#define QKH_D  192
#define VD_D   128
#define MROWS  (BB*SS)           // 4096 token rows

typedef __attribute__((ext_vector_type(8))) short bf16x8;   // 8 bf16 (4 VGPRs)
typedef __attribute__((ext_vector_type(4))) float f32x4;    // MFMA accumulator

__device__ inline float bf2f(unsigned short u) {
    union { float f; unsigned int i; } v; v.i = ((unsigned int)u) << 16; return v.f;
}
__device__ inline unsigned short f2bf(float f) {
    union { float f; unsigned int u; } v; v.f = f;
    unsigned int r = v.u + 0x7fffu + ((v.u >> 16) & 1u);
    return (unsigned short)(r >> 16);
}

// async global->LDS, 16 B per lane.  LDS dest = wave-uniform base + lane*16.
__device__ __forceinline__ void gload_lds16(const ushort* g, ushort* l)
{
    __builtin_amdgcn_global_load_lds(
        (const __attribute__((address_space(1))) void*)(g),
        (__attribute__((address_space(3))) void*)(l), 16, 0, 0);
}

// ---------------------------------------------------------------------------
// One-launch f32 -> bf16 convert of all 6 tensors.
// ---------------------------------------------------------------------------
__global__ void conv6(const float* s0, ushort* d0, int n0,
                      const float* s1, ushort* d1, int n1,
                      const float* s2, ushort* d2, int n2,
                      const float* s3, ushort* d3, int n3,
                      const float* s4, ushort* d4, int n4,
                      const float* s5, ushort* d5, int n5)
{
    const int st = gridDim.x * 256;
    const int t0 = blockIdx.x * 256 + threadIdx.x;
    for (int i = t0; i < n0; i += st) { float4 v = ((const float4*)s0)[i]; ushort4 u; u.x=f2bf(v.x);u.y=f2bf(v.y);u.z=f2bf(v.z);u.w=f2bf(v.w); ((ushort4*)d0)[i]=u; }
    for (int i = t0; i < n1; i += st) { float4 v = ((const float4*)s1)[i]; ushort4 u; u.x=f2bf(v.x);u.y=f2bf(v.y);u.z=f2bf(v.z);u.w=f2bf(v.w); ((ushort4*)d1)[i]=u; }
    for (int i = t0; i < n2; i += st) { float4 v = ((const float4*)s2)[i]; ushort4 u; u.x=f2bf(v.x);u.y=f2bf(v.y);u.z=f2bf(v.z);u.w=f2bf(v.w); ((ushort4*)d2)[i]=u; }
    for (int i = t0; i < n3; i += st) { float4 v = ((const float4*)s3)[i]; ushort4 u; u.x=f2bf(v.x);u.y=f2bf(v.y);u.z=f2bf(v.z);u.w=f2bf(v.w); ((ushort4*)d3)[i]=u; }
    for (int i = t0; i < n4; i += st) { float4 v = ((const float4*)s4)[i]; ushort4 u; u.x=f2bf(v.x);u.y=f2bf(v.y);u.z=f2bf(v.z);u.w=f2bf(v.w); ((ushort4*)d4)[i]=u; }
    for (int i = t0; i < n5; i += st) { float4 v = ((const float4*)s5)[i]; ushort4 u; u.x=f2bf(v.x);u.y=f2bf(v.y);u.z=f2bf(v.z);u.w=f2bf(v.w); ((ushort4*)d5)[i]=u; }
}

// ---------------------------------------------------------------------------
// All-bf16 MFMA NT GEMM: 128x128 tile, BK=64, coalesced swizzled
// global_load_lds staging.  M mult of 128; N guarded; K mult of 64.
// ---------------------------------------------------------------------------
template<typename TC>
__launch_bounds__(256, 3)
__global__ void gemm_bf(const ushort* __restrict__ A, int lda, size_t Ab, size_t Ah,
                        const ushort* __restrict__ B, int ldb, size_t Bb, size_t Bh,
                        const float* __restrict__ bias,
                        TC* __restrict__ C, int ldc, size_t Cb, size_t Ch,
                        int M, int N, int K)
{
    __shared__ ushort As[128 * 64];
    __shared__ ushort Bs[128 * 64];
    const int z = blockIdx.z, bz = z >> 4, hz = z & 15;
    A += (size_t)bz * Ab + (size_t)hz * Ah;
    B += (size_t)bz * Bb + (size_t)hz * Bh;
    C += (size_t)bz * Cb + (size_t)hz * Ch;
    const int m0 = blockIdx.y * 128, n0 = blockIdx.x * 128;
    const int tid = threadIdx.x, w = tid >> 6, lane = tid & 63;
    const int l15 = lane & 15, q = lane >> 4;
    const int r7 = lane >> 3, c7 = lane & 7;
    const int xork = l15 & 7;

    f32x4 acc[4][4];
#pragma unroll
    for (int i = 0; i < 4; i++)
#pragma unroll
        for (int j = 0; j < 4; j++) acc[i][j] = (f32x4){0.f, 0.f, 0.f, 0.f};

    const int mrow = 64 * (w & 1) + l15;
    const int nrow = 64 * (w >> 1) + l15;

    for (int k0 = 0; k0 < K; k0 += 64) {
#pragma unroll
        for (int i = 0; i < 4; i++) {
            int g = 4 * w + i;
            int row = g * 8 + r7;
            int ch = c7 ^ r7;
            gload_lds16(A + (size_t)(m0 + row) * lda + k0 + ch * 8,
                        As + g * 512 + lane * 8);
            int rb = n0 + row; if (rb > N - 1) rb = N - 1;
            gload_lds16(B + (size_t)rb * ldb + k0 + ch * 8,
                        Bs + g * 512 + lane * 8);
        }
        __syncthreads();
#pragma unroll
        for (int ks = 0; ks < 2; ks++) {
            bf16x8 af[4], bf[4];
            const int chx = (ks * 4 + q) ^ xork;
#pragma unroll
            for (int mt = 0; mt < 4; mt++)
                af[mt] = *(const bf16x8*)(As + (mrow + 16 * mt) * 64 + chx * 8);
#pragma unroll
            for (int nt = 0; nt < 4; nt++)
                bf[nt] = *(const bf16x8*)(Bs + (nrow + 16 * nt) * 64 + chx * 8);
#pragma unroll
            for (int mt = 0; mt < 4; mt++)
#pragma unroll
                for (int nt = 0; nt < 4; nt++)
                    acc[mt][nt] = __builtin_amdgcn_mfma_f32_16x16x32_bf16(af[mt], bf[nt], acc[mt][nt], 0, 0, 0);
        }
        __syncthreads();
    }

#pragma unroll
    for (int nt = 0; nt < 4; nt++) {
        int n = n0 + nrow + 16 * nt;
        if (n >= N) continue;
        float bv = bias ? bias[n] : 0.f;
#pragma unroll
        for (int mt = 0; mt < 4; mt++) {
#pragma unroll
            for (int r = 0; r < 4; r++) {
                int m = m0 + 64 * (w & 1) + 16 * mt + 4 * q + r;
                float v = acc[mt][nt][r] + bv;
                if constexpr (sizeof(TC) == 2) C[(size_t)m * ldc + n] = f2bf(v);
                else                           C[(size_t)m * ldc + n] = v;
            }
        }
    }
}

// ---------------------------------------------------------------------------
// RMSNorm bf16 in-place.  One 256-thread block per row.
// ---------------------------------------------------------------------------
__launch_bounds__(256)
__global__ void rmsnorm_bf16(ushort* __restrict__ x, const float* __restrict__ w, int width)
{
    ushort* xr = x + (size_t)blockIdx.x * width;
    float ss = 0.f;
    for (int i = threadIdx.x; i < width; i += 256) { float v = bf2f(xr[i]); ss += v * v; }
    __shared__ float red[256];
    red[threadIdx.x] = ss; __syncthreads();
    for (int off = 128; off > 0; off >>= 1) {
        if (threadIdx.x < off) red[threadIdx.x] += red[threadIdx.x + off];
        __syncthreads();
    }
    float r = rsqrtf(red[0] / (float)width + 1e-6f);
    for (int i = threadIdx.x; i < width; i += 256)
        xr[i] = f2bf(w[i] * bf2f(xr[i]) * r);
}

__device__ inline float rope_val(float xj, float xo, int j, int s)
{
    int i = j & 31;
    float freq = powf(10000.f, -(float)i / 32.f);
    float a = (float)s * freq;
    float sn, cs; sincosf(a, &sn, &cs);
    float other = (j < 32) ? -xo : xo;
    return xj * cs + other * sn;
}

// kv finalize: rms_norm latent 512 + rope pe 64, bf16 in -> kvbf bf16
__launch_bounds__(256)
__global__ void finalize_kv(const ushort* __restrict__ kvf, const float* __restrict__ w,
                            ushort* __restrict__ kvbf)
{
    int m = blockIdx.x, s = m & (SS - 1);
    const ushort* xr = kvf + (size_t)m * 576;
    float ss = 0.f;
    for (int i = threadIdx.x; i < 512; i += 256) { float v = bf2f(xr[i]); ss += v * v; }
    __shared__ float red[256];
    red[threadIdx.x] = ss; __syncthreads();
    for (int off = 128; off > 0; off >>= 1) {
        if (threadIdx.x < off) red[threadIdx.x] += red[threadIdx.x + off];
        __syncthreads();
    }
    float r = rsqrtf(red[0] / 512.f + 1e-6f);
    for (int i = threadIdx.x; i < 512; i += 256)
        kvbf[(size_t)m * 576 + i] = f2bf(w[i] * bf2f(xr[i]) * r);
    if (threadIdx.x < 64) {
        int j = threadIdx.x;
        float xj = bf2f(xr[512 + j]), xo = bf2f(xr[512 + (j ^ 32)]);
        kvbf[(size_t)m * 576 + 512 + j] = f2bf(rope_val(xj, xo, j, s));
    }
}

// RoPE q_pe in place on qbuf bf16.  grid (4096,4) x 256; wave owns one head.
__global__ void rope_q_kernel(ushort* __restrict__ qbuf)
{
    int m = blockIdx.x, s = m & (SS - 1);
    int w = threadIdx.x >> 6, j = threadIdx.x & 63;
    int h = blockIdx.y * 4 + w;
    ushort* p = qbuf + (size_t)m * 3072 + h * QKH_D + NOPE_D;
    float xj = bf2f(p[j]);
    float xo = bf2f(p[j ^ 32]);
    p[j] = f2bf(rope_val(xj, xo, j, s));
}

// ---------------------------------------------------------------------------
// MFMA flash attention, TRANSPOSED dataflow (verified R0 structure):
//   S^T = K·Q^T  (s on lane axis, t on register axis)
//   -> softmax: in-register reduce over 16 t + 2 shfl_xor (16,32); m/l/alpha
//      are one scalar per lane.
//   O^T = V^T·P^T: V^T tile staged in shared LDS; P^T via wave-private LDS
//      slab PLACED IN THE DEAD Kt REGION (Kt is only read during QK^T).
//      A mid barrier [2] separates all QK^T reads of Kt from P stores.
//      LDS = Kt 24,576 + Vt 16,384 = 40,960 B -> 4 blocks/CU (was 3).
//   Element accesses (P store/read, K/V reads, softmax) are byte-identical
//      to the verified R0 kernel; only the Ptw base + barrier [2] changed.
//   XCD remap (bijective): bid&7 = XCD, 4 bh per XCD for K/V L2 locality.
// ---------------------------------------------------------------------------
#define SCL  0.10411760f  // (1/sqrt(192)) * log2(e)
#define PTL  72
#define NJOB 45

__constant__ unsigned char JQT[NJOB] = {18,17,16,19,20,21,22,23,24,25,26,27,28,29,30,31,15,31,14,30,13,29,12,28,11,27,10,26,9,25,8,24,7,23,6,22,5,21,4,20,3,19,2,1,0};
__constant__ unsigned char JT0[NJOB] = { 0, 0, 0, 0, 0, 0, 0, 0, 0, 0, 0, 0, 0, 0, 0, 0, 0,16, 0,16, 0,16, 0,16, 0,16, 0,16, 0,16, 0,16, 0,16, 0,16, 0,16, 0,16, 0,16, 0, 0, 0};
__constant__ unsigned char JT1[NJOB] = {19,18,17,16,16,16,16,16,16,16,16,16,16,16,16,16,16,32,15,31,14,30,13,29,12,28,11,27,10,26, 9,25, 8,24, 7,23, 6,22, 5,21, 4,20, 3, 2, 1};

__device__ __forceinline__ int ktidx(int row, int ch) {
    return (((ch >> 3) << 3) + (row >> 3)) * 512 + (row & 7) * 64 + (((ch & 7) ^ (row & 7)) << 3);
}
// Vt: 16 groups of 8 d-rows; slot swizzle chunk^(d&7)
__device__ __forceinline__ int vtidx(int d, int ch) {
    return (d >> 3) * 512 + (d & 7) * 64 + ((ch ^ (d & 7)) << 3);
}

__launch_bounds__(256, 4)
__global__ void attn_mfma(const ushort* __restrict__ qbuf, const ushort* __restrict__ Kf,
                          const ushort* __restrict__ kvbf, const ushort* __restrict__ VT,
                          const int* __restrict__ mask, ushort* __restrict__ o_heads,
                          ushort* __restrict__ Opart, float2* __restrict__ mlbuf)
{
    __shared__ ushort Kt[24 * 512];      // 24,576 B shared K-tile (64 t x 192)
    __shared__ ushort Vt[16 * 512];      // 16,384 B shared V^T tile (128 d x 64 t)
                                         // total 40,960 B -> 4 blocks/CU
    const int tid = threadIdx.x, w = tid >> 6, lane = tid & 63;
    const int l15 = lane & 15, q = lane >> 4;
    const int r7 = lane >> 3, c7 = lane & 7;

    // XCD-aware decode (bijective): xcd = bid&7; bh = xcd + 8*(ii&3); job = ii>>2
    const int bid = blockIdx.x;
    const int xcd = bid & 7, ii = bid >> 3;
    const int bh = xcd + ((ii & 3) << 3);
    const int job = ii >> 2;
    const int b = bh >> 4, h = bh & 15;
    const int qt = JQT[job], t0s = JT0[job], t1s = JT1[job];
    const int s0 = qt * 64;
    const bool partial = (t0s != 0) | (t1s != qt + 1);

    const ushort* Kf_bh = Kf + (size_t)bh * SS * NOPE_D;
    const ushort* VT_bh = VT + (size_t)bh * VD_D * SS;
    const ushort* kpe_b = kvbf + (size_t)b * SS * 576 + 512;
    const int* mrow = mask + b * SS;
    ushort* Ptw = Kt + w * 16 * PTL;     // wave-private P^T slab in dead Kt region

    // Q B-frags: rows s0+16w..+15 (n = lane&15), 6 k-chunks of 32 over 192 dims
    bf16x8 qf[6];
    {
        const ushort* qbase = qbuf + ((size_t)(b * SS) + s0 + 16 * w + l15) * 3072 + h * QKH_D + q * 8;
#pragma unroll
        for (int k = 0; k < 6; k++) qf[k] = *(const bf16x8*)(qbase + k * 32);
    }

    f32x4 Oacc[8];   // O^T: rows d = 16nt+4q+r, col s = l15
#pragma unroll
    for (int nt = 0; nt < 8; nt++) Oacc[nt] = (f32x4){0.f, 0.f, 0.f, 0.f};
    float m_i = -3e38f, l_i = 0.f;
    const int my_s = s0 + 16 * w + l15;

    for (int st = t0s; st < t1s; st++) {
        const int t0 = st * 64;
        // ---- stage K-tile (24 groups) + V^T tile (16 groups); wave w: 6 K + 4 V ----
#pragma unroll
        for (int i = 0; i < 6; i++) {
            int g = 6 * w + i;
            int rg = g & 7, cg = g >> 3;
            int row = rg * 8 + r7;
            int chl = c7 ^ r7;
            const ushort* src = (cg < 2)
                ? Kf_bh + (size_t)(t0 + row) * NOPE_D + (cg * 8 + chl) * 8
                : kpe_b + (size_t)(t0 + row) * 576 + chl * 8;
            gload_lds16(src, Kt + g * 512 + lane * 8);
        }
#pragma unroll
        for (int i = 0; i < 4; i++) {
            int g = 4 * w + i;                  // d-group 0..15
            int d = g * 8 + r7;
            gload_lds16(VT_bh + (size_t)d * SS + t0 + ((c7 ^ r7) << 3),
                        Vt + g * 512 + lane * 8);
        }
        __syncthreads();                         // [1] tiles staged (vmcnt drained)
        // ---- scores S^T(64 t x 16 s): sa[c] rows t=16c+4q+r, col s=l15 ----
        f32x4 sa[4];
#pragma unroll
        for (int c = 0; c < 4; c++) sa[c] = (f32x4){0.f, 0.f, 0.f, 0.f};
        __builtin_amdgcn_s_setprio(1);
#pragma unroll
        for (int k = 0; k < 6; k++) {
#pragma unroll
            for (int c = 0; c < 4; c++) {
                bf16x8 kb = *(const bf16x8*)(Kt + ktidx(16 * c + l15, 4 * k + q));
                sa[c] = __builtin_amdgcn_mfma_f32_16x16x32_bf16(kb, qf[k], sa[c], 0, 0, 0);
            }
        }
        __builtin_amdgcn_s_setprio(0);
        __syncthreads();                         // [2] all QK reads of Kt done;
                                                 //     Kt region now P scratch
        // ---- softmax: in-register over t, 2 shfl over s-duplicated quads ----
        float sc[4][4];
        float mx = -3e38f;
#pragma unroll
        for (int c = 0; c < 4; c++) {
            int4 mv4 = *(const int4*)&mrow[t0 + 16 * c + 4 * q];
#pragma unroll
            for (int r = 0; r < 4; r++) {
                int t = t0 + 16 * c + 4 * q + r;
                float v = sa[c][r] * SCL;
                int mvr = (&mv4.x)[r];
                if (t > my_s || mvr == 0) v = -1e30f;
                sc[c][r] = v;
                mx = fmaxf(mx, v);
            }
        }
        mx = fmaxf(mx, __shfl_xor(mx, 16));
        mx = fmaxf(mx, __shfl_xor(mx, 32));
        float mn = fmaxf(m_i, mx);
        float alpha = exp2f(m_i - mn);
        m_i = mn;
        float ps = 0.f;
#pragma unroll
        for (int c = 0; c < 4; c++) {
            ushort4 pk;
#pragma unroll
            for (int r = 0; r < 4; r++) {
                float p = (sc[c][r] <= -1e29f) ? 0.f : exp2f(sc[c][r] - mn);
                ps += p;
                (&pk.x)[r] = f2bf(p);
            }
            *(ushort4*)(Ptw + l15 * PTL + 16 * c + 4 * q) = pk;
        }
        ps += __shfl_xor(ps, 16);
        ps += __shfl_xor(ps, 32);
        l_i = l_i * alpha + ps;
        // ---- rescale O^T (scalar per lane) ----
#pragma unroll
        for (int nt = 0; nt < 8; nt++) {
            Oacc[nt][0] *= alpha; Oacc[nt][1] *= alpha;
            Oacc[nt][2] *= alpha; Oacc[nt][3] *= alpha;
        }
        // ---- PV: O^T(128 d x 16 s) += V^T(LDS) @ P^T(wave LDS slab) ----
        bf16x8 pb[2];
#pragma unroll
        for (int kt = 0; kt < 2; kt++)
            pb[kt] = *(const bf16x8*)(Ptw + l15 * PTL + kt * 32 + q * 8);
        __builtin_amdgcn_s_setprio(1);
#pragma unroll
        for (int nt = 0; nt < 8; nt++) {
#pragma unroll
            for (int kt = 0; kt < 2; kt++) {
                bf16x8 vf = *(const bf16x8*)(Vt + vtidx(16 * nt + l15, kt * 4 + q));
                Oacc[nt] = __builtin_amdgcn_mfma_f32_16x16x32_bf16(vf, pb[kt], Oacc[nt], 0, 0, 0);
            }
        }
        __builtin_amdgcn_s_setprio(0);
        __syncthreads();                         // [3] Vt/Ptw reads done; next stage safe
    }

    // ---- epilogue (intra-wave; O^T rows d = 16nt+4q+r, col s = l15) ----
    float lv = (l_i > 0.f) ? 1.f / l_i : 0.f;

    if (!partial) {
        ushort* orow = o_heads + (size_t)(b * SS + my_s) * 2048 + h * VD_D;
#pragma unroll
        for (int nt = 0; nt < 8; nt++) {
            ushort4 pk;
            pk.x = f2bf(Oacc[nt][0] * lv); pk.y = f2bf(Oacc[nt][1] * lv);
            pk.z = f2bf(Oacc[nt][2] * lv); pk.w = f2bf(Oacc[nt][3] * lv);
            *(ushort4*)(orow + 16 * nt + 4 * q) = pk;
        }
    } else {
        const int sp = (t0s != 0);
        const int p = bh * 26 + (qt - 19) * 2 + sp;
        const int rl = 16 * w + l15;
        ushort* prow = Opart + ((size_t)p * 64 + rl) * 128;
#pragma unroll
        for (int nt = 0; nt < 8; nt++) {
            ushort4 pk;
            pk.x = f2bf(Oacc[nt][0] * lv); pk.y = f2bf(Oacc[nt][1] * lv);
            pk.z = f2bf(Oacc[nt][2] * lv); pk.w = f2bf(Oacc[nt][3] * lv);
            *(ushort4*)(prow + 16 * nt + 4 * q) = pk;
        }
        if (lane < 16)
            mlbuf[p * 64 + rl] = make_float2(m_i, l_i);
    }
}

// ---------------------------------------------------------------------------
// Merge span0/span1 partials for qt>=19.  grid 416 (= 32bh x 13qt) x 256.
// ---------------------------------------------------------------------------
__launch_bounds__(256)
__global__ void attn_merge(const ushort* __restrict__ Opart, const float2* __restrict__ mlbuf,
                           ushort* __restrict__ o_heads)
{
    int bh = blockIdx.x & 31, qi = blockIdx.x >> 5;
    int b = bh >> 4, h = bh & 15;
    int qt = 19 + qi;
    int t = threadIdx.x;
    int row = t >> 2, dbase = (t & 3) * 32;
    int p0 = bh * 26 + qi * 2, p1 = p0 + 1;
    float2 ml0 = mlbuf[p0 * 64 + row], ml1 = mlbuf[p1 * 64 + row];
    float M = fmaxf(ml0.x, ml1.x);
    float w0 = (ml0.y > 0.f) ? exp2f(ml0.x - M) * ml0.y : 0.f;
    float w1 = (ml1.y > 0.f) ? exp2f(ml1.x - M) * ml1.y : 0.f;
    float den = w0 + w1;
    float inv = (den > 0.f) ? 1.f / den : 0.f;
    w0 *= inv; w1 *= inv;
    int s = qt * 64 + row;
    const ushort* O0 = Opart + ((size_t)p0 * 64 + row) * 128 + dbase;
    const ushort* O1 = Opart + ((size_t)p1 * 64 + row) * 128 + dbase;
    ushort* dst = o_heads + (size_t)(b * SS + s) * 2048 + h * VD_D + dbase;
#pragma unroll
    for (int c = 0; c < 32; c += 8) {
        bf16x8 a = *(const bf16x8*)(O0 + c);
        bf16x8 bb = *(const bf16x8*)(O1 + c);
        bf16x8 o;
#pragma unroll
        for (int j = 0; j < 8; j++)
            o[j] = (short)f2bf(w0 * bf2f((unsigned short)a[j]) + w1 * bf2f((unsigned short)bb[j]));
        *(bf16x8*)(dst + c) = o;
    }
}

extern "C" void kernel_launch(void* const* d_in, const int* in_sizes, int n_in,
                              void* d_out, int out_size, void* d_ws, size_t ws_size,
                              hipStream_t stream)
{
    const float* x        = (const float*)d_in[0];
    const int*   mask     = (const int*)d_in[1];
    const float* wq_a_w   = (const float*)d_in[2];
    const float* wq_a_b   = (const float*)d_in[3];
    const float* q_norm_w = (const float*)d_in[4];
    const float* wq_b_w   = (const float*)d_in[5];
    const float* wq_b_b   = (const float*)d_in[6];
    const float* wkv_a_w  = (const float*)d_in[7];
    const float* wkv_a_b  = (const float*)d_in[8];
    const float* kv_norm_w= (const float*)d_in[9];
    const float* wkv_b_w  = (const float*)d_in[10];
    const float* wo_w     = (const float*)d_in[11];
    const float* wo_b     = (const float*)d_in[12];
    float* out = (float*)d_out;

    // Workspace (peak 102,662,144 B) — layout identical to R0
    char* W = (char*)d_ws;
    ushort* wo_bf    = (ushort*)(W + 0);
    ushort* qbuf     = (ushort*)(W + 8388608);
    ushort* wq_b_bf  = (ushort*)(W + 33554432);
    ushort* Kf       = (ushort*)(W + 33554432);
    ushort* wq_a_bf  = (ushort*)(W + 42991616);
    ushort* kvfull_bf= (ushort*)(W + 42991616);
    ushort* x_bf     = (ushort*)(W + 50331648);
    ushort* VT       = (ushort*)(W + 50331648);
    ushort* q_a_bf   = (ushort*)(W + 67108864);
    ushort* o_heads  = (ushort*)(W + 67108864);
    ushort* wkv_a_bf = (ushort*)(W + 79691776);
    ushort* wkv_b_bf = (ushort*)(W + 83886080);
    ushort* Opart    = (ushort*)(W + 83886080);
    float2* mlbuf    = (float2*)(W + 97517568);
    ushort* kvbf     = (ushort*)(W + 97943552);

    // 0. all f32->bf16 converts, one launch
    conv6<<<4096, 256, 0, stream>>>(
        x, x_bf, MROWS * HH / 4,
        wq_a_w, wq_a_bf, QLL * HH / 4,
        wq_b_w, wq_b_bf, 3072 * QLL / 4,
        wkv_a_w, wkv_a_bf, 576 * HH / 4,
        wkv_b_w, wkv_b_bf, NHH * 256 * 512 / 4,
        wo_w, wo_bf, HH * 2048 / 4);

    // 1. q_a = x @ wq_a^T + b  -> bf16
    gemm_bf<ushort><<<dim3(QLL/128, MROWS/128, 1), 256, 0, stream>>>(
        x_bf, HH, 0, 0, wq_a_bf, HH, 0, 0, wq_a_b, q_a_bf, QLL, 0, 0, MROWS, QLL, HH);
    // 2. rms_norm in place (bf16)
    rmsnorm_bf16<<<MROWS, 256, 0, stream>>>(q_a_bf, q_norm_w, QLL);
    // 3. q = q_a @ wq_b^T + b -> qbuf bf16
    gemm_bf<ushort><<<dim3(3072/128, MROWS/128, 1), 256, 0, stream>>>(
        q_a_bf, QLL, 0, 0, wq_b_bf, QLL, 0, 0, wq_b_b, qbuf, 3072, 0, 0, MROWS, 3072, QLL);
    // 4. kv_full = x @ wkv_a^T + b -> bf16 (N=576 guarded)
    gemm_bf<ushort><<<dim3(5, MROWS/128, 1), 256, 0, stream>>>(
        x_bf, HH, 0, 0, wkv_a_bf, HH, 0, 0, wkv_a_b, kvfull_bf, 576, 0, 0, MROWS, 576, HH);
    // 5. finalize kv (rms + rope) -> kvbf
    finalize_kv<<<MROWS, 256, 0, stream>>>(kvfull_bf, kv_norm_w, kvbf);
    // 6. rope q_pe in place on qbuf
    rope_q_kernel<<<dim3(MROWS, 4), 256, 0, stream>>>(qbuf);
    // 7. Kf[b,h] = kv_lat @ W_UK[h]^T  (nope only; M=2048,N=128,K=512, z=32)
    gemm_bf<ushort><<<dim3(1, SS/128, 32), 256, 0, stream>>>(
        kvbf, 576, (size_t)SS * 576, 0,
        wkv_b_bf, 512, 0, (size_t)256 * 512,
        nullptr, Kf, NOPE_D, (size_t)NHH * SS * NOPE_D, (size_t)SS * NOPE_D,
        SS, NOPE_D, 512);
    // 9. VT[b,h] = W_UV[h] @ kv_lat^T  (M=128,N=2048,K=512, z=32)
    gemm_bf<ushort><<<dim3(SS/128, 1, 32), 256, 0, stream>>>(
        wkv_b_bf + (size_t)128 * 512, 512, 0, (size_t)256 * 512,
        kvbf, 576, (size_t)SS * 576, 0,
        nullptr, VT, SS, (size_t)NHH * VD_D * SS, (size_t)VD_D * SS,
        VD_D, SS, 512);
    // 10. split-K MFMA flash attention (1440 blocks) + merge
    attn_mfma<<<NJOB * 32, 256, 0, stream>>>(qbuf, Kf, kvbf, VT, mask, o_heads, Opart, mlbuf);
    attn_merge<<<13 * 32, 256, 0, stream>>>(Opart, mlbuf, o_heads);
    // 12. out = o_heads @ wo^T + b
    gemm_bf<float><<<dim3(HH/128, MROWS/128, 1), 256, 0, stream>>>(
        o_heads, NHH * VD_D, 0, 0, wo_bf, NHH * VD_D, 0, 0, wo_b, out, HH, 0, 0,
        MROWS, HH, NHH * VD_D);
}

// Round 4
// 479.127 us; speedup vs baseline: 1.1569x; 1.1569x over previous
//
#include <hip/hip_runtime.h>
#include <hip/hip_bf16.h>

#define BB   2
#define SS   2048
#define HH   2048
#define NHH  16
#define QLL  1536
#define KVLL 512
#define NOPE_D 128
#define ROPE_D 64
#define QKH_D  192
#define VD_D   128
#define MROWS  (BB*SS)           // 4096 token rows

typedef __attribute__((ext_vector_type(8))) short bf16x8;   // 8 bf16 (4 VGPRs)
typedef __attribute__((ext_vector_type(4))) float f32x4;    // MFMA accumulator

__device__ inline float bf2f(unsigned short u) {
    union { float f; unsigned int i; } v; v.i = ((unsigned int)u) << 16; return v.f;
}
__device__ inline unsigned short f2bf(float f) {
    union { float f; unsigned int u; } v; v.f = f;
    unsigned int r = v.u + 0x7fffu + ((v.u >> 16) & 1u);
    return (unsigned short)(r >> 16);
}

// async global->LDS, 16 B per lane.  LDS dest = wave-uniform base + lane*16.
__device__ __forceinline__ void gload_lds16(const ushort* g, ushort* l)
{
    __builtin_amdgcn_global_load_lds(
        (const __attribute__((address_space(1))) void*)(g),
        (__attribute__((address_space(3))) void*)(l), 16, 0, 0);
}

// ---------------------------------------------------------------------------
// One-launch f32 -> bf16 convert of all 6 tensors.
// ---------------------------------------------------------------------------
__global__ void conv6(const float* s0, ushort* d0, int n0,
                      const float* s1, ushort* d1, int n1,
                      const float* s2, ushort* d2, int n2,
                      const float* s3, ushort* d3, int n3,
                      const float* s4, ushort* d4, int n4,
                      const float* s5, ushort* d5, int n5)
{
    const int st = gridDim.x * 256;
    const int t0 = blockIdx.x * 256 + threadIdx.x;
    for (int i = t0; i < n0; i += st) { float4 v = ((const float4*)s0)[i]; ushort4 u; u.x=f2bf(v.x);u.y=f2bf(v.y);u.z=f2bf(v.z);u.w=f2bf(v.w); ((ushort4*)d0)[i]=u; }
    for (int i = t0; i < n1; i += st) { float4 v = ((const float4*)s1)[i]; ushort4 u; u.x=f2bf(v.x);u.y=f2bf(v.y);u.z=f2bf(v.z);u.w=f2bf(v.w); ((ushort4*)d1)[i]=u; }
    for (int i = t0; i < n2; i += st) { float4 v = ((const float4*)s2)[i]; ushort4 u; u.x=f2bf(v.x);u.y=f2bf(v.y);u.z=f2bf(v.z);u.w=f2bf(v.w); ((ushort4*)d2)[i]=u; }
    for (int i = t0; i < n3; i += st) { float4 v = ((const float4*)s3)[i]; ushort4 u; u.x=f2bf(v.x);u.y=f2bf(v.y);u.z=f2bf(v.z);u.w=f2bf(v.w); ((ushort4*)d3)[i]=u; }
    for (int i = t0; i < n4; i += st) { float4 v = ((const float4*)s4)[i]; ushort4 u; u.x=f2bf(v.x);u.y=f2bf(v.y);u.z=f2bf(v.z);u.w=f2bf(v.w); ((ushort4*)d4)[i]=u; }
    for (int i = t0; i < n5; i += st) { float4 v = ((const float4*)s5)[i]; ushort4 u; u.x=f2bf(v.x);u.y=f2bf(v.y);u.z=f2bf(v.z);u.w=f2bf(v.w); ((ushort4*)d5)[i]=u; }
}

// ---------------------------------------------------------------------------
// All-bf16 MFMA NT GEMM: 128x128 tile, BK=64, coalesced swizzled
// global_load_lds staging.  M mult of 128; N guarded; K mult of 64.
// XCD swizzle (z==1, nwg%8==0): each XCD owns a contiguous M-chunk so the
// A-panels stay resident in its private L2 (was: every y-row sprayed
// round-robin across all 8 XCDs -> 8x A traffic from L3).
// ---------------------------------------------------------------------------
template<typename TC>
__launch_bounds__(256, 3)
__global__ void gemm_bf(const ushort* __restrict__ A, int lda, size_t Ab, size_t Ah,
                        const ushort* __restrict__ B, int ldb, size_t Bb, size_t Bh,
                        const float* __restrict__ bias,
                        TC* __restrict__ C, int ldc, size_t Cb, size_t Ch,
                        int M, int N, int K)
{
    __shared__ ushort As[128 * 64];
    __shared__ ushort Bs[128 * 64];
    const int z = blockIdx.z, bz = z >> 4, hz = z & 15;
    A += (size_t)bz * Ab + (size_t)hz * Ah;
    B += (size_t)bz * Bb + (size_t)hz * Bh;
    C += (size_t)bz * Cb + (size_t)hz * Ch;
    int bx = blockIdx.x, by = blockIdx.y;
    if (gridDim.z == 1) {
        const int gx = gridDim.x, nwg = gx * gridDim.y;
        if ((nwg & 7) == 0) {
            int lin = by * gx + bx;                       // HW dispatch order
            int swz = (lin & 7) * (nwg >> 3) + (lin >> 3); // bijection: XCD-chunked
            bx = swz % gx; by = swz / gx;
        }
    }
    const int m0 = by * 128, n0 = bx * 128;
    const int tid = threadIdx.x, w = tid >> 6, lane = tid & 63;
    const int l15 = lane & 15, q = lane >> 4;
    const int r7 = lane >> 3, c7 = lane & 7;
    const int xork = l15 & 7;

    f32x4 acc[4][4];
#pragma unroll
    for (int i = 0; i < 4; i++)
#pragma unroll
        for (int j = 0; j < 4; j++) acc[i][j] = (f32x4){0.f, 0.f, 0.f, 0.f};

    const int mrow = 64 * (w & 1) + l15;
    const int nrow = 64 * (w >> 1) + l15;

    for (int k0 = 0; k0 < K; k0 += 64) {
#pragma unroll
        for (int i = 0; i < 4; i++) {
            int g = 4 * w + i;
            int row = g * 8 + r7;
            int ch = c7 ^ r7;
            gload_lds16(A + (size_t)(m0 + row) * lda + k0 + ch * 8,
                        As + g * 512 + lane * 8);
            int rb = n0 + row; if (rb > N - 1) rb = N - 1;
            gload_lds16(B + (size_t)rb * ldb + k0 + ch * 8,
                        Bs + g * 512 + lane * 8);
        }
        __syncthreads();
#pragma unroll
        for (int ks = 0; ks < 2; ks++) {
            bf16x8 af[4], bf[4];
            const int chx = (ks * 4 + q) ^ xork;
#pragma unroll
            for (int mt = 0; mt < 4; mt++)
                af[mt] = *(const bf16x8*)(As + (mrow + 16 * mt) * 64 + chx * 8);
#pragma unroll
            for (int nt = 0; nt < 4; nt++)
                bf[nt] = *(const bf16x8*)(Bs + (nrow + 16 * nt) * 64 + chx * 8);
#pragma unroll
            for (int mt = 0; mt < 4; mt++)
#pragma unroll
                for (int nt = 0; nt < 4; nt++)
                    acc[mt][nt] = __builtin_amdgcn_mfma_f32_16x16x32_bf16(af[mt], bf[nt], acc[mt][nt], 0, 0, 0);
        }
        __syncthreads();
    }

#pragma unroll
    for (int nt = 0; nt < 4; nt++) {
        int n = n0 + nrow + 16 * nt;
        if (n >= N) continue;
        float bv = bias ? bias[n] : 0.f;
#pragma unroll
        for (int mt = 0; mt < 4; mt++) {
#pragma unroll
            for (int r = 0; r < 4; r++) {
                int m = m0 + 64 * (w & 1) + 16 * mt + 4 * q + r;
                float v = acc[mt][nt][r] + bv;
                if constexpr (sizeof(TC) == 2) C[(size_t)m * ldc + n] = f2bf(v);
                else                           C[(size_t)m * ldc + n] = v;
            }
        }
    }
}

// ---------------------------------------------------------------------------
// RMSNorm bf16 in-place.  One 256-thread block per row.
// ---------------------------------------------------------------------------
__launch_bounds__(256)
__global__ void rmsnorm_bf16(ushort* __restrict__ x, const float* __restrict__ w, int width)
{
    ushort* xr = x + (size_t)blockIdx.x * width;
    float ss = 0.f;
    for (int i = threadIdx.x; i < width; i += 256) { float v = bf2f(xr[i]); ss += v * v; }
    __shared__ float red[256];
    red[threadIdx.x] = ss; __syncthreads();
    for (int off = 128; off > 0; off >>= 1) {
        if (threadIdx.x < off) red[threadIdx.x] += red[threadIdx.x + off];
        __syncthreads();
    }
    float r = rsqrtf(red[0] / (float)width + 1e-6f);
    for (int i = threadIdx.x; i < width; i += 256)
        xr[i] = f2bf(w[i] * bf2f(xr[i]) * r);
}

__device__ inline float rope_val(float xj, float xo, int j, int s)
{
    int i = j & 31;
    float freq = powf(10000.f, -(float)i / 32.f);
    float a = (float)s * freq;
    float sn, cs; sincosf(a, &sn, &cs);
    float other = (j < 32) ? -xo : xo;
    return xj * cs + other * sn;
}

// kv finalize: rms_norm latent 512 + rope pe 64, bf16 in -> kvbf bf16
__launch_bounds__(256)
__global__ void finalize_kv(const ushort* __restrict__ kvf, const float* __restrict__ w,
                            ushort* __restrict__ kvbf)
{
    int m = blockIdx.x, s = m & (SS - 1);
    const ushort* xr = kvf + (size_t)m * 576;
    float ss = 0.f;
    for (int i = threadIdx.x; i < 512; i += 256) { float v = bf2f(xr[i]); ss += v * v; }
    __shared__ float red[256];
    red[threadIdx.x] = ss; __syncthreads();
    for (int off = 128; off > 0; off >>= 1) {
        if (threadIdx.x < off) red[threadIdx.x] += red[threadIdx.x + off];
        __syncthreads();
    }
    float r = rsqrtf(red[0] / 512.f + 1e-6f);
    for (int i = threadIdx.x; i < 512; i += 256)
        kvbf[(size_t)m * 576 + i] = f2bf(w[i] * bf2f(xr[i]) * r);
    if (threadIdx.x < 64) {
        int j = threadIdx.x;
        float xj = bf2f(xr[512 + j]), xo = bf2f(xr[512 + (j ^ 32)]);
        kvbf[(size_t)m * 576 + 512 + j] = f2bf(rope_val(xj, xo, j, s));
    }
}

// RoPE q_pe in place on qbuf bf16.  grid (4096,4) x 256; wave owns one head.
__global__ void rope_q_kernel(ushort* __restrict__ qbuf)
{
    int m = blockIdx.x, s = m & (SS - 1);
    int w = threadIdx.x >> 6, j = threadIdx.x & 63;
    int h = blockIdx.y * 4 + w;
    ushort* p = qbuf + (size_t)m * 3072 + h * QKH_D + NOPE_D;
    float xj = bf2f(p[j]);
    float xo = bf2f(p[j ^ 32]);
    p[j] = f2bf(rope_val(xj, xo, j, s));
}

// ---------------------------------------------------------------------------
// MFMA flash attention — R0-verified structure (Pt own slab, 50,176 B LDS,
// 3 blocks/CU, 2 barriers/step).  R4 exact-semantics VALU diet:
//   * tree-max (fmax associative) instead of 32-deep serial chain
//   * skip O-rescale when __all(mx <= m_i)  (alpha==1 identity, THR=0 exact)
//   * unguarded exp2f: exp2f(-1e30 - mn) == 0 exactly (mn finite every step)
//   * s_setprio(1) around both MFMA clusters (T5, refcheck'd in R3)
// NOTE (R3 lesson): do NOT raise occupancy to 4/CU — per-XCD staging
// working set exceeds 4 MB L2 and FETCH_SIZE triples (48->139 MB).
// ---------------------------------------------------------------------------
#define SCL  0.10411760f  // (1/sqrt(192)) * log2(e)
#define PTL  72
#define NJOB 45

__constant__ unsigned char JQT[NJOB] = {18,17,16,19,20,21,22,23,24,25,26,27,28,29,30,31,15,31,14,30,13,29,12,28,11,27,10,26,9,25,8,24,7,23,6,22,5,21,4,20,3,19,2,1,0};
__constant__ unsigned char JT0[NJOB] = { 0, 0, 0, 0, 0, 0, 0, 0, 0, 0, 0, 0, 0, 0, 0, 0, 0,16, 0,16, 0,16, 0,16, 0,16, 0,16, 0,16, 0,16, 0,16, 0,16, 0,16, 0,16, 0,16, 0, 0, 0};
__constant__ unsigned char JT1[NJOB] = {19,18,17,16,16,16,16,16,16,16,16,16,16,16,16,16,16,32,15,31,14,30,13,29,12,28,11,27,10,26, 9,25, 8,24, 7,23, 6,22, 5,21, 4,20, 3, 2, 1};

__device__ __forceinline__ int ktidx(int row, int ch) {
    return (((ch >> 3) << 3) + (row >> 3)) * 512 + (row & 7) * 64 + (((ch & 7) ^ (row & 7)) << 3);
}
// Vt: 16 groups of 8 d-rows; slot swizzle chunk^(d&7)
__device__ __forceinline__ int vtidx(int d, int ch) {
    return (d >> 3) * 512 + (d & 7) * 64 + ((ch ^ (d & 7)) << 3);
}

__launch_bounds__(256, 3)
__global__ void attn_mfma(const ushort* __restrict__ qbuf, const ushort* __restrict__ Kf,
                          const ushort* __restrict__ kvbf, const ushort* __restrict__ VT,
                          const int* __restrict__ mask, ushort* __restrict__ o_heads,
                          ushort* __restrict__ Opart, float2* __restrict__ mlbuf)
{
    __shared__ ushort Kt[24 * 512];      // 24,576 B shared K-tile (64 t x 192)
    __shared__ ushort Vt[16 * 512];      // 16,384 B shared V^T tile (128 d x 64 t)
    __shared__ ushort Pt[4 * 16 * PTL];  //  9,216 B wave-private P^T slabs

    const int tid = threadIdx.x, w = tid >> 6, lane = tid & 63;
    const int l15 = lane & 15, q = lane >> 4;
    const int r7 = lane >> 3, c7 = lane & 7;

    const int job = blockIdx.x >> 5, bh = blockIdx.x & 31;
    const int b = bh >> 4, h = bh & 15;
    const int qt = JQT[job], t0s = JT0[job], t1s = JT1[job];
    const int s0 = qt * 64;
    const bool partial = (t0s != 0) | (t1s != qt + 1);

    const ushort* Kf_bh = Kf + (size_t)bh * SS * NOPE_D;
    const ushort* VT_bh = VT + (size_t)bh * VD_D * SS;
    const ushort* kpe_b = kvbf + (size_t)b * SS * 576 + 512;
    const int* mrow = mask + b * SS;
    ushort* Ptw = Pt + w * 16 * PTL;

    // Q B-frags: rows s0+16w..+15 (n = lane&15), 6 k-chunks of 32 over 192 dims
    bf16x8 qf[6];
    {
        const ushort* qbase = qbuf + ((size_t)(b * SS) + s0 + 16 * w + l15) * 3072 + h * QKH_D + q * 8;
#pragma unroll
        for (int k = 0; k < 6; k++) qf[k] = *(const bf16x8*)(qbase + k * 32);
    }

    f32x4 Oacc[8];   // O^T: rows d = 16nt+4q+r, col s = l15
#pragma unroll
    for (int nt = 0; nt < 8; nt++) Oacc[nt] = (f32x4){0.f, 0.f, 0.f, 0.f};
    float m_i = -3e38f, l_i = 0.f;
    const int my_s = s0 + 16 * w + l15;

    for (int st = t0s; st < t1s; st++) {
        const int t0 = st * 64;
        // ---- stage K-tile (24 groups) + V^T tile (16 groups); wave w: 6 K + 4 V ----
#pragma unroll
        for (int i = 0; i < 6; i++) {
            int g = 6 * w + i;
            int rg = g & 7, cg = g >> 3;
            int row = rg * 8 + r7;
            int chl = c7 ^ r7;
            const ushort* src = (cg < 2)
                ? Kf_bh + (size_t)(t0 + row) * NOPE_D + (cg * 8 + chl) * 8
                : kpe_b + (size_t)(t0 + row) * 576 + chl * 8;
            gload_lds16(src, Kt + g * 512 + lane * 8);
        }
#pragma unroll
        for (int i = 0; i < 4; i++) {
            int g = 4 * w + i;                  // d-group 0..15
            int d = g * 8 + r7;
            gload_lds16(VT_bh + (size_t)d * SS + t0 + ((c7 ^ r7) << 3),
                        Vt + g * 512 + lane * 8);
        }
        __syncthreads();
        // ---- scores S^T(64 t x 16 s): sa[c] rows t=16c+4q+r, col s=l15 ----
        f32x4 sa[4];
#pragma unroll
        for (int c = 0; c < 4; c++) sa[c] = (f32x4){0.f, 0.f, 0.f, 0.f};
        __builtin_amdgcn_s_setprio(1);
#pragma unroll
        for (int k = 0; k < 6; k++) {
#pragma unroll
            for (int c = 0; c < 4; c++) {
                bf16x8 kb = *(const bf16x8*)(Kt + ktidx(16 * c + l15, 4 * k + q));
                sa[c] = __builtin_amdgcn_mfma_f32_16x16x32_bf16(kb, qf[k], sa[c], 0, 0, 0);
            }
        }
        __builtin_amdgcn_s_setprio(0);
        // ---- masked scores ----
        float sc[4][4];
#pragma unroll
        for (int c = 0; c < 4; c++) {
            int4 mv4 = *(const int4*)&mrow[t0 + 16 * c + 4 * q];
#pragma unroll
            for (int r = 0; r < 4; r++) {
                int t = t0 + 16 * c + 4 * q + r;
                float v = sa[c][r] * SCL;
                int mvr = (&mv4.x)[r];
                if (t > my_s || mvr == 0) v = -1e30f;
                sc[c][r] = v;
            }
        }
        // ---- tree max (exact; fmax associative) + cross-quad reduce ----
        float mx = fmaxf(
            fmaxf(fmaxf(fmaxf(sc[0][0], sc[0][1]), fmaxf(sc[0][2], sc[0][3])),
                  fmaxf(fmaxf(sc[1][0], sc[1][1]), fmaxf(sc[1][2], sc[1][3]))),
            fmaxf(fmaxf(fmaxf(sc[2][0], sc[2][1]), fmaxf(sc[2][2], sc[2][3])),
                  fmaxf(fmaxf(sc[3][0], sc[3][1]), fmaxf(sc[3][2], sc[3][3]))));
        mx = fmaxf(mx, __shfl_xor(mx, 16));
        mx = fmaxf(mx, __shfl_xor(mx, 32));
        float mn = fmaxf(m_i, mx);
        // skip rescale when alpha==1 for ALL lanes (identity; THR=0, exact)
        if (!__all(mx <= m_i)) {
            float alpha = exp2f(m_i - mn);
            l_i *= alpha;
#pragma unroll
            for (int nt = 0; nt < 8; nt++) {
                Oacc[nt][0] *= alpha; Oacc[nt][1] *= alpha;
                Oacc[nt][2] *= alpha; Oacc[nt][3] *= alpha;
            }
        }
        m_i = mn;
        // ---- P = exp2(sc - mn); masked entries underflow to exactly 0 ----
        float ps = 0.f;
#pragma unroll
        for (int c = 0; c < 4; c++) {
            ushort4 pk;
#pragma unroll
            for (int r = 0; r < 4; r++) {
                float p = exp2f(sc[c][r] - mn);
                ps += p;
                (&pk.x)[r] = f2bf(p);
            }
            *(ushort4*)(Ptw + l15 * PTL + 16 * c + 4 * q) = pk;
        }
        ps += __shfl_xor(ps, 16);
        ps += __shfl_xor(ps, 32);
        l_i += ps;
        // ---- PV: O^T(128 d x 16 s) += V^T(LDS) @ P^T(wave LDS) ----
        bf16x8 pb[2];
#pragma unroll
        for (int kt = 0; kt < 2; kt++)
            pb[kt] = *(const bf16x8*)(Ptw + l15 * PTL + kt * 32 + q * 8);
        __builtin_amdgcn_s_setprio(1);
#pragma unroll
        for (int nt = 0; nt < 8; nt++) {
#pragma unroll
            for (int kt = 0; kt < 2; kt++) {
                bf16x8 vf = *(const bf16x8*)(Vt + vtidx(16 * nt + l15, kt * 4 + q));
                Oacc[nt] = __builtin_amdgcn_mfma_f32_16x16x32_bf16(vf, pb[kt], Oacc[nt], 0, 0, 0);
            }
        }
        __builtin_amdgcn_s_setprio(0);
        __syncthreads();   // protect Kt/Vt for next step
    }

    // ---- epilogue (intra-wave; O^T rows d = 16nt+4q+r, col s = l15) ----
    float lv = (l_i > 0.f) ? 1.f / l_i : 0.f;

    if (!partial) {
        ushort* orow = o_heads + (size_t)(b * SS + my_s) * 2048 + h * VD_D;
#pragma unroll
        for (int nt = 0; nt < 8; nt++) {
            ushort4 pk;
            pk.x = f2bf(Oacc[nt][0] * lv); pk.y = f2bf(Oacc[nt][1] * lv);
            pk.z = f2bf(Oacc[nt][2] * lv); pk.w = f2bf(Oacc[nt][3] * lv);
            *(ushort4*)(orow + 16 * nt + 4 * q) = pk;
        }
    } else {
        const int sp = (t0s != 0);
        const int p = bh * 26 + (qt - 19) * 2 + sp;
        const int rl = 16 * w + l15;
        ushort* prow = Opart + ((size_t)p * 64 + rl) * 128;
#pragma unroll
        for (int nt = 0; nt < 8; nt++) {
            ushort4 pk;
            pk.x = f2bf(Oacc[nt][0] * lv); pk.y = f2bf(Oacc[nt][1] * lv);
            pk.z = f2bf(Oacc[nt][2] * lv); pk.w = f2bf(Oacc[nt][3] * lv);
            *(ushort4*)(prow + 16 * nt + 4 * q) = pk;
        }
        if (lane < 16)
            mlbuf[p * 64 + rl] = make_float2(m_i, l_i);
    }
}

// ---------------------------------------------------------------------------
// Merge span0/span1 partials for qt>=19.  grid 416 (= 32bh x 13qt) x 256.
// ---------------------------------------------------------------------------
__launch_bounds__(256)
__global__ void attn_merge(const ushort* __restrict__ Opart, const float2* __restrict__ mlbuf,
                           ushort* __restrict__ o_heads)
{
    int bh = blockIdx.x & 31, qi = blockIdx.x >> 5;
    int b = bh >> 4, h = bh & 15;
    int qt = 19 + qi;
    int t = threadIdx.x;
    int row = t >> 2, dbase = (t & 3) * 32;
    int p0 = bh * 26 + qi * 2, p1 = p0 + 1;
    float2 ml0 = mlbuf[p0 * 64 + row], ml1 = mlbuf[p1 * 64 + row];
    float M = fmaxf(ml0.x, ml1.x);
    float w0 = (ml0.y > 0.f) ? exp2f(ml0.x - M) * ml0.y : 0.f;
    float w1 = (ml1.y > 0.f) ? exp2f(ml1.x - M) * ml1.y : 0.f;
    float den = w0 + w1;
    float inv = (den > 0.f) ? 1.f / den : 0.f;
    w0 *= inv; w1 *= inv;
    int s = qt * 64 + row;
    const ushort* O0 = Opart + ((size_t)p0 * 64 + row) * 128 + dbase;
    const ushort* O1 = Opart + ((size_t)p1 * 64 + row) * 128 + dbase;
    ushort* dst = o_heads + (size_t)(b * SS + s) * 2048 + h * VD_D + dbase;
#pragma unroll
    for (int c = 0; c < 32; c += 8) {
        bf16x8 a = *(const bf16x8*)(O0 + c);
        bf16x8 bb = *(const bf16x8*)(O1 + c);
        bf16x8 o;
#pragma unroll
        for (int j = 0; j < 8; j++)
            o[j] = (short)f2bf(w0 * bf2f((unsigned short)a[j]) + w1 * bf2f((unsigned short)bb[j]));
        *(bf16x8*)(dst + c) = o;
    }
}

extern "C" void kernel_launch(void* const* d_in, const int* in_sizes, int n_in,
                              void* d_out, int out_size, void* d_ws, size_t ws_size,
                              hipStream_t stream)
{
    const float* x        = (const float*)d_in[0];
    const int*   mask     = (const int*)d_in[1];
    const float* wq_a_w   = (const float*)d_in[2];
    const float* wq_a_b   = (const float*)d_in[3];
    const float* q_norm_w = (const float*)d_in[4];
    const float* wq_b_w   = (const float*)d_in[5];
    const float* wq_b_b   = (const float*)d_in[6];
    const float* wkv_a_w  = (const float*)d_in[7];
    const float* wkv_a_b  = (const float*)d_in[8];
    const float* kv_norm_w= (const float*)d_in[9];
    const float* wkv_b_w  = (const float*)d_in[10];
    const float* wo_w     = (const float*)d_in[11];
    const float* wo_b     = (const float*)d_in[12];
    float* out = (float*)d_out;

    // Workspace (peak 102,662,144 B) — layout identical to R0
    char* W = (char*)d_ws;
    ushort* wo_bf    = (ushort*)(W + 0);
    ushort* qbuf     = (ushort*)(W + 8388608);
    ushort* wq_b_bf  = (ushort*)(W + 33554432);
    ushort* Kf       = (ushort*)(W + 33554432);
    ushort* wq_a_bf  = (ushort*)(W + 42991616);
    ushort* kvfull_bf= (ushort*)(W + 42991616);
    ushort* x_bf     = (ushort*)(W + 50331648);
    ushort* VT       = (ushort*)(W + 50331648);
    ushort* q_a_bf   = (ushort*)(W + 67108864);
    ushort* o_heads  = (ushort*)(W + 67108864);
    ushort* wkv_a_bf = (ushort*)(W + 79691776);
    ushort* wkv_b_bf = (ushort*)(W + 83886080);
    ushort* Opart    = (ushort*)(W + 83886080);
    float2* mlbuf    = (float2*)(W + 97517568);
    ushort* kvbf     = (ushort*)(W + 97943552);

    // 0. all f32->bf16 converts, one launch
    conv6<<<4096, 256, 0, stream>>>(
        x, x_bf, MROWS * HH / 4,
        wq_a_w, wq_a_bf, QLL * HH / 4,
        wq_b_w, wq_b_bf, 3072 * QLL / 4,
        wkv_a_w, wkv_a_bf, 576 * HH / 4,
        wkv_b_w, wkv_b_bf, NHH * 256 * 512 / 4,
        wo_w, wo_bf, HH * 2048 / 4);

    // 1. q_a = x @ wq_a^T + b  -> bf16
    gemm_bf<ushort><<<dim3(QLL/128, MROWS/128, 1), 256, 0, stream>>>(
        x_bf, HH, 0, 0, wq_a_bf, HH, 0, 0, wq_a_b, q_a_bf, QLL, 0, 0, MROWS, QLL, HH);
    // 2. rms_norm in place (bf16)
    rmsnorm_bf16<<<MROWS, 256, 0, stream>>>(q_a_bf, q_norm_w, QLL);
    // 3. q = q_a @ wq_b^T + b -> qbuf bf16
    gemm_bf<ushort><<<dim3(3072/128, MROWS/128, 1), 256, 0, stream>>>(
        q_a_bf, QLL, 0, 0, wq_b_bf, QLL, 0, 0, wq_b_b, qbuf, 3072, 0, 0, MROWS, 3072, QLL);
    // 4. kv_full = x @ wkv_a^T + b -> bf16 (N=576 guarded)
    gemm_bf<ushort><<<dim3(5, MROWS/128, 1), 256, 0, stream>>>(
        x_bf, HH, 0, 0, wkv_a_bf, HH, 0, 0, wkv_a_b, kvfull_bf, 576, 0, 0, MROWS, 576, HH);
    // 5. finalize kv (rms + rope) -> kvbf
    finalize_kv<<<MROWS, 256, 0, stream>>>(kvfull_bf, kv_norm_w, kvbf);
    // 6. rope q_pe in place on qbuf
    rope_q_kernel<<<dim3(MROWS, 4), 256, 0, stream>>>(qbuf);
    // 7. Kf[b,h] = kv_lat @ W_UK[h]^T  (nope only; M=2048,N=128,K=512, z=32)
    gemm_bf<ushort><<<dim3(1, SS/128, 32), 256, 0, stream>>>(
        kvbf, 576, (size_t)SS * 576, 0,
        wkv_b_bf, 512, 0, (size_t)256 * 512,
        nullptr, Kf, NOPE_D, (size_t)NHH * SS * NOPE_D, (size_t)SS * NOPE_D,
        SS, NOPE_D, 512);
    // 9. VT[b,h] = W_UV[h] @ kv_lat^T  (M=128,N=2048,K=512, z=32)
    gemm_bf<ushort><<<dim3(SS/128, 1, 32), 256, 0, stream>>>(
        wkv_b_bf + (size_t)128 * 512, 512, 0, (size_t)256 * 512,
        kvbf, 576, (size_t)SS * 576, 0,
        nullptr, VT, SS, (size_t)NHH * VD_D * SS, (size_t)VD_D * SS,
        VD_D, SS, 512);
    // 10. split-K MFMA flash attention (1440 blocks) + merge
    attn_mfma<<<NJOB * 32, 256, 0, stream>>>(qbuf, Kf, kvbf, VT, mask, o_heads, Opart, mlbuf);
    attn_merge<<<13 * 32, 256, 0, stream>>>(Opart, mlbuf, o_heads);
    // 12. out = o_heads @ wo^T + b
    gemm_bf<float><<<dim3(HH/128, MROWS/128, 1), 256, 0, stream>>>(
        o_heads, NHH * VD_D, 0, 0, wo_bf, NHH * VD_D, 0, 0, wo_b, out, HH, 0, 0,
        MROWS, HH, NHH * VD_D);
}

// Round 5
// 477.962 us; speedup vs baseline: 1.1597x; 1.0024x over previous
//
#include <hip/hip_runtime.h>
#include <hip/hip_bf16.h>

#define BB   2
#define SS   2048
#define HH   2048
#define NHH  16
#define QLL  1536
#define KVLL 512
#define NOPE_D 128
#define ROPE_D 64
#define QKH_D  192
#define VD_D   128
#define MROWS  (BB*SS)           // 4096 token rows

typedef __attribute__((ext_vector_type(8))) short bf16x8;   // 8 bf16 (4 VGPRs)
typedef __attribute__((ext_vector_type(4))) float f32x4;    // MFMA accumulator

__device__ inline float bf2f(unsigned short u) {
    union { float f; unsigned int i; } v; v.i = ((unsigned int)u) << 16; return v.f;
}
__device__ inline unsigned short f2bf(float f) {
    union { float f; unsigned int u; } v; v.f = f;
    unsigned int r = v.u + 0x7fffu + ((v.u >> 16) & 1u);
    return (unsigned short)(r >> 16);
}
// HW packed f32->bf16 (RNE): dst.lo = bf16(src0), dst.hi = bf16(src1)
// (guide T12 recipe operand order, HW-verified m214v22)
__device__ __forceinline__ unsigned int cvtpk(float lo, float hi) {
    unsigned int r;
    asm("v_cvt_pk_bf16_f32 %0, %1, %2" : "=v"(r) : "v"(lo), "v"(hi));
    return r;
}

// async global->LDS, 16 B per lane.  LDS dest = wave-uniform base + lane*16.
__device__ __forceinline__ void gload_lds16(const ushort* g, ushort* l)
{
    __builtin_amdgcn_global_load_lds(
        (const __attribute__((address_space(1))) void*)(g),
        (__attribute__((address_space(3))) void*)(l), 16, 0, 0);
}

// ---------------------------------------------------------------------------
// One-launch f32 -> bf16 convert of all 6 tensors.
// ---------------------------------------------------------------------------
__global__ void conv6(const float* s0, ushort* d0, int n0,
                      const float* s1, ushort* d1, int n1,
                      const float* s2, ushort* d2, int n2,
                      const float* s3, ushort* d3, int n3,
                      const float* s4, ushort* d4, int n4,
                      const float* s5, ushort* d5, int n5)
{
    const int st = gridDim.x * 256;
    const int t0 = blockIdx.x * 256 + threadIdx.x;
    for (int i = t0; i < n0; i += st) { float4 v = ((const float4*)s0)[i]; ushort4 u; u.x=f2bf(v.x);u.y=f2bf(v.y);u.z=f2bf(v.z);u.w=f2bf(v.w); ((ushort4*)d0)[i]=u; }
    for (int i = t0; i < n1; i += st) { float4 v = ((const float4*)s1)[i]; ushort4 u; u.x=f2bf(v.x);u.y=f2bf(v.y);u.z=f2bf(v.z);u.w=f2bf(v.w); ((ushort4*)d1)[i]=u; }
    for (int i = t0; i < n2; i += st) { float4 v = ((const float4*)s2)[i]; ushort4 u; u.x=f2bf(v.x);u.y=f2bf(v.y);u.z=f2bf(v.z);u.w=f2bf(v.w); ((ushort4*)d2)[i]=u; }
    for (int i = t0; i < n3; i += st) { float4 v = ((const float4*)s3)[i]; ushort4 u; u.x=f2bf(v.x);u.y=f2bf(v.y);u.z=f2bf(v.z);u.w=f2bf(v.w); ((ushort4*)d3)[i]=u; }
    for (int i = t0; i < n4; i += st) { float4 v = ((const float4*)s4)[i]; ushort4 u; u.x=f2bf(v.x);u.y=f2bf(v.y);u.z=f2bf(v.z);u.w=f2bf(v.w); ((ushort4*)d4)[i]=u; }
    for (int i = t0; i < n5; i += st) { float4 v = ((const float4*)s5)[i]; ushort4 u; u.x=f2bf(v.x);u.y=f2bf(v.y);u.z=f2bf(v.z);u.w=f2bf(v.w); ((ushort4*)d5)[i]=u; }
}

// ---------------------------------------------------------------------------
// All-bf16 MFMA NT GEMM: 128x128 tile, BK=64, coalesced swizzled
// global_load_lds staging.  M mult of 128; N guarded; K mult of 64.
// NOTE (R4 lesson): no XCD blockIdx swizzle — operands are L3-resident at
// these sizes and the swizzle measured ~+7 us net (m160-consistent).
// ---------------------------------------------------------------------------
template<typename TC>
__launch_bounds__(256, 3)
__global__ void gemm_bf(const ushort* __restrict__ A, int lda, size_t Ab, size_t Ah,
                        const ushort* __restrict__ B, int ldb, size_t Bb, size_t Bh,
                        const float* __restrict__ bias,
                        TC* __restrict__ C, int ldc, size_t Cb, size_t Ch,
                        int M, int N, int K)
{
    __shared__ ushort As[128 * 64];
    __shared__ ushort Bs[128 * 64];
    const int z = blockIdx.z, bz = z >> 4, hz = z & 15;
    A += (size_t)bz * Ab + (size_t)hz * Ah;
    B += (size_t)bz * Bb + (size_t)hz * Bh;
    C += (size_t)bz * Cb + (size_t)hz * Ch;
    const int m0 = blockIdx.y * 128, n0 = blockIdx.x * 128;
    const int tid = threadIdx.x, w = tid >> 6, lane = tid & 63;
    const int l15 = lane & 15, q = lane >> 4;
    const int r7 = lane >> 3, c7 = lane & 7;
    const int xork = l15 & 7;

    f32x4 acc[4][4];
#pragma unroll
    for (int i = 0; i < 4; i++)
#pragma unroll
        for (int j = 0; j < 4; j++) acc[i][j] = (f32x4){0.f, 0.f, 0.f, 0.f};

    const int mrow = 64 * (w & 1) + l15;
    const int nrow = 64 * (w >> 1) + l15;

    for (int k0 = 0; k0 < K; k0 += 64) {
#pragma unroll
        for (int i = 0; i < 4; i++) {
            int g = 4 * w + i;
            int row = g * 8 + r7;
            int ch = c7 ^ r7;
            gload_lds16(A + (size_t)(m0 + row) * lda + k0 + ch * 8,
                        As + g * 512 + lane * 8);
            int rb = n0 + row; if (rb > N - 1) rb = N - 1;
            gload_lds16(B + (size_t)rb * ldb + k0 + ch * 8,
                        Bs + g * 512 + lane * 8);
        }
        __syncthreads();
#pragma unroll
        for (int ks = 0; ks < 2; ks++) {
            bf16x8 af[4], bf[4];
            const int chx = (ks * 4 + q) ^ xork;
#pragma unroll
            for (int mt = 0; mt < 4; mt++)
                af[mt] = *(const bf16x8*)(As + (mrow + 16 * mt) * 64 + chx * 8);
#pragma unroll
            for (int nt = 0; nt < 4; nt++)
                bf[nt] = *(const bf16x8*)(Bs + (nrow + 16 * nt) * 64 + chx * 8);
#pragma unroll
            for (int mt = 0; mt < 4; mt++)
#pragma unroll
                for (int nt = 0; nt < 4; nt++)
                    acc[mt][nt] = __builtin_amdgcn_mfma_f32_16x16x32_bf16(af[mt], bf[nt], acc[mt][nt], 0, 0, 0);
        }
        __syncthreads();
    }

#pragma unroll
    for (int nt = 0; nt < 4; nt++) {
        int n = n0 + nrow + 16 * nt;
        if (n >= N) continue;
        float bv = bias ? bias[n] : 0.f;
#pragma unroll
        for (int mt = 0; mt < 4; mt++) {
#pragma unroll
            for (int r = 0; r < 4; r++) {
                int m = m0 + 64 * (w & 1) + 16 * mt + 4 * q + r;
                float v = acc[mt][nt][r] + bv;
                if constexpr (sizeof(TC) == 2) C[(size_t)m * ldc + n] = f2bf(v);
                else                           C[(size_t)m * ldc + n] = v;
            }
        }
    }
}

// ---------------------------------------------------------------------------
// RMSNorm bf16 in-place, vectorized (ushort4 / float4).  width mult of 4.
// ---------------------------------------------------------------------------
__launch_bounds__(256)
__global__ void rmsnorm_bf16(ushort* __restrict__ x, const float* __restrict__ w, int width)
{
    ushort* xr = x + (size_t)blockIdx.x * width;
    const int w4 = width >> 2;
    float ss = 0.f;
    for (int i = threadIdx.x; i < w4; i += 256) {
        ushort4 v = ((const ushort4*)xr)[i];
        float a = bf2f(v.x), b = bf2f(v.y), c = bf2f(v.z), d = bf2f(v.w);
        ss += (a * a + b * b) + (c * c + d * d);
    }
    __shared__ float red[256];
    red[threadIdx.x] = ss; __syncthreads();
    for (int off = 128; off > 0; off >>= 1) {
        if (threadIdx.x < off) red[threadIdx.x] += red[threadIdx.x + off];
        __syncthreads();
    }
    float r = rsqrtf(red[0] / (float)width + 1e-6f);
    for (int i = threadIdx.x; i < w4; i += 256) {
        ushort4 v = ((const ushort4*)xr)[i];
        float4 wv = ((const float4*)w)[i];
        ushort4 o;
        o.x = f2bf(wv.x * bf2f(v.x) * r);
        o.y = f2bf(wv.y * bf2f(v.y) * r);
        o.z = f2bf(wv.z * bf2f(v.z) * r);
        o.w = f2bf(wv.w * bf2f(v.w) * r);
        ((ushort4*)xr)[i] = o;
    }
}

__device__ inline float rope_val(float xj, float xo, int j, int s)
{
    int i = j & 31;
    float freq = powf(10000.f, -(float)i / 32.f);
    float a = (float)s * freq;
    float sn, cs; sincosf(a, &sn, &cs);
    float other = (j < 32) ? -xo : xo;
    return xj * cs + other * sn;
}

// kv finalize: rms_norm latent 512 + rope pe 64, bf16 in -> kvbf bf16
__launch_bounds__(256)
__global__ void finalize_kv(const ushort* __restrict__ kvf, const float* __restrict__ w,
                            ushort* __restrict__ kvbf)
{
    int m = blockIdx.x, s = m & (SS - 1);
    const ushort* xr = kvf + (size_t)m * 576;
    float ss = 0.f;
    for (int i = threadIdx.x; i < 128; i += 256) {
        ushort4 v = ((const ushort4*)xr)[i];
        float a = bf2f(v.x), b = bf2f(v.y), c = bf2f(v.z), d = bf2f(v.w);
        ss += (a * a + b * b) + (c * c + d * d);
    }
    __shared__ float red[256];
    red[threadIdx.x] = ss; __syncthreads();
    for (int off = 128; off > 0; off >>= 1) {
        if (threadIdx.x < off) red[threadIdx.x] += red[threadIdx.x + off];
        __syncthreads();
    }
    float r = rsqrtf(red[0] / 512.f + 1e-6f);
    ushort* dr = kvbf + (size_t)m * 576;
    for (int i = threadIdx.x; i < 128; i += 256) {
        ushort4 v = ((const ushort4*)xr)[i];
        float4 wv = ((const float4*)w)[i];
        ushort4 o;
        o.x = f2bf(wv.x * bf2f(v.x) * r);
        o.y = f2bf(wv.y * bf2f(v.y) * r);
        o.z = f2bf(wv.z * bf2f(v.z) * r);
        o.w = f2bf(wv.w * bf2f(v.w) * r);
        ((ushort4*)dr)[i] = o;
    }
    if (threadIdx.x < 64) {
        int j = threadIdx.x;
        float xj = bf2f(xr[512 + j]), xo = bf2f(xr[512 + (j ^ 32)]);
        dr[512 + j] = f2bf(rope_val(xj, xo, j, s));
    }
}

// RoPE q_pe in place on qbuf bf16.  grid (4096,4) x 256; wave owns one head.
__global__ void rope_q_kernel(ushort* __restrict__ qbuf)
{
    int m = blockIdx.x, s = m & (SS - 1);
    int w = threadIdx.x >> 6, j = threadIdx.x & 63;
    int h = blockIdx.y * 4 + w;
    ushort* p = qbuf + (size_t)m * 3072 + h * QKH_D + NOPE_D;
    float xj = bf2f(p[j]);
    float xo = bf2f(p[j ^ 32]);
    p[j] = f2bf(rope_val(xj, xo, j, s));
}

// ---------------------------------------------------------------------------
// MFMA flash attention — R0-verified structure (Pt own slab, 50,176 B LDS,
// 3 blocks/CU, 2 barriers/step) + R4 VALU diet + R5:
//   * causal check hoisted to the diagonal tile only (st==qt); for st<qt,
//     t <= st*64+63 <= s0-1 < my_s, so the check is provably never true.
//   * P packing via v_cvt_pk_bf16_f32 (1 op/pair vs 3 ops/elem f2bf).
// NOTE (R3 lesson): keep 3 blocks/CU — 4/CU blows the per-XCD L2 working
// set (FETCH 48->139 MB).  NOTE (R1/R2 lesson): shuffle-P stays dead.
// ---------------------------------------------------------------------------
#define SCL  0.10411760f  // (1/sqrt(192)) * log2(e)
#define PTL  72
#define NJOB 45

__constant__ unsigned char JQT[NJOB] = {18,17,16,19,20,21,22,23,24,25,26,27,28,29,30,31,15,31,14,30,13,29,12,28,11,27,10,26,9,25,8,24,7,23,6,22,5,21,4,20,3,19,2,1,0};
__constant__ unsigned char JT0[NJOB] = { 0, 0, 0, 0, 0, 0, 0, 0, 0, 0, 0, 0, 0, 0, 0, 0, 0,16, 0,16, 0,16, 0,16, 0,16, 0,16, 0,16, 0,16, 0,16, 0,16, 0,16, 0,16, 0,16, 0, 0, 0};
__constant__ unsigned char JT1[NJOB] = {19,18,17,16,16,16,16,16,16,16,16,16,16,16,16,16,16,32,15,31,14,30,13,29,12,28,11,27,10,26, 9,25, 8,24, 7,23, 6,22, 5,21, 4,20, 3, 2, 1};

__device__ __forceinline__ int ktidx(int row, int ch) {
    return (((ch >> 3) << 3) + (row >> 3)) * 512 + (row & 7) * 64 + (((ch & 7) ^ (row & 7)) << 3);
}
// Vt: 16 groups of 8 d-rows; slot swizzle chunk^(d&7)
__device__ __forceinline__ int vtidx(int d, int ch) {
    return (d >> 3) * 512 + (d & 7) * 64 + ((ch ^ (d & 7)) << 3);
}

__launch_bounds__(256, 3)
__global__ void attn_mfma(const ushort* __restrict__ qbuf, const ushort* __restrict__ Kf,
                          const ushort* __restrict__ kvbf, const ushort* __restrict__ VT,
                          const int* __restrict__ mask, ushort* __restrict__ o_heads,
                          ushort* __restrict__ Opart, float2* __restrict__ mlbuf)
{
    __shared__ ushort Kt[24 * 512];      // 24,576 B shared K-tile (64 t x 192)
    __shared__ ushort Vt[16 * 512];      // 16,384 B shared V^T tile (128 d x 64 t)
    __shared__ ushort Pt[4 * 16 * PTL];  //  9,216 B wave-private P^T slabs

    const int tid = threadIdx.x, w = tid >> 6, lane = tid & 63;
    const int l15 = lane & 15, q = lane >> 4;
    const int r7 = lane >> 3, c7 = lane & 7;

    const int job = blockIdx.x >> 5, bh = blockIdx.x & 31;
    const int b = bh >> 4, h = bh & 15;
    const int qt = JQT[job], t0s = JT0[job], t1s = JT1[job];
    const int s0 = qt * 64;
    const bool partial = (t0s != 0) | (t1s != qt + 1);

    const ushort* Kf_bh = Kf + (size_t)bh * SS * NOPE_D;
    const ushort* VT_bh = VT + (size_t)bh * VD_D * SS;
    const ushort* kpe_b = kvbf + (size_t)b * SS * 576 + 512;
    const int* mrow = mask + b * SS;
    ushort* Ptw = Pt + w * 16 * PTL;

    // Q B-frags: rows s0+16w..+15 (n = lane&15), 6 k-chunks of 32 over 192 dims
    bf16x8 qf[6];
    {
        const ushort* qbase = qbuf + ((size_t)(b * SS) + s0 + 16 * w + l15) * 3072 + h * QKH_D + q * 8;
#pragma unroll
        for (int k = 0; k < 6; k++) qf[k] = *(const bf16x8*)(qbase + k * 32);
    }

    f32x4 Oacc[8];   // O^T: rows d = 16nt+4q+r, col s = l15
#pragma unroll
    for (int nt = 0; nt < 8; nt++) Oacc[nt] = (f32x4){0.f, 0.f, 0.f, 0.f};
    float m_i = -3e38f, l_i = 0.f;
    const int my_s = s0 + 16 * w + l15;

    for (int st = t0s; st < t1s; st++) {
        const int t0 = st * 64;
        // ---- stage K-tile (24 groups) + V^T tile (16 groups); wave w: 6 K + 4 V ----
#pragma unroll
        for (int i = 0; i < 6; i++) {
            int g = 6 * w + i;
            int rg = g & 7, cg = g >> 3;
            int row = rg * 8 + r7;
            int chl = c7 ^ r7;
            const ushort* src = (cg < 2)
                ? Kf_bh + (size_t)(t0 + row) * NOPE_D + (cg * 8 + chl) * 8
                : kpe_b + (size_t)(t0 + row) * 576 + chl * 8;
            gload_lds16(src, Kt + g * 512 + lane * 8);
        }
#pragma unroll
        for (int i = 0; i < 4; i++) {
            int g = 4 * w + i;                  // d-group 0..15
            int d = g * 8 + r7;
            gload_lds16(VT_bh + (size_t)d * SS + t0 + ((c7 ^ r7) << 3),
                        Vt + g * 512 + lane * 8);
        }
        __syncthreads();
        // ---- scores S^T(64 t x 16 s): sa[c] rows t=16c+4q+r, col s=l15 ----
        f32x4 sa[4];
#pragma unroll
        for (int c = 0; c < 4; c++) sa[c] = (f32x4){0.f, 0.f, 0.f, 0.f};
        __builtin_amdgcn_s_setprio(1);
#pragma unroll
        for (int k = 0; k < 6; k++) {
#pragma unroll
            for (int c = 0; c < 4; c++) {
                bf16x8 kb = *(const bf16x8*)(Kt + ktidx(16 * c + l15, 4 * k + q));
                sa[c] = __builtin_amdgcn_mfma_f32_16x16x32_bf16(kb, qf[k], sa[c], 0, 0, 0);
            }
        }
        __builtin_amdgcn_s_setprio(0);
        // ---- masked scores: causal only on the diagonal tile (st==qt) ----
        float sc[4][4];
        if (st == qt) {
#pragma unroll
            for (int c = 0; c < 4; c++) {
                int4 mv4 = *(const int4*)&mrow[t0 + 16 * c + 4 * q];
#pragma unroll
                for (int r = 0; r < 4; r++) {
                    int t = t0 + 16 * c + 4 * q + r;
                    float v = sa[c][r] * SCL;
                    if (t > my_s || (&mv4.x)[r] == 0) v = -1e30f;
                    sc[c][r] = v;
                }
            }
        } else {
#pragma unroll
            for (int c = 0; c < 4; c++) {
                int4 mv4 = *(const int4*)&mrow[t0 + 16 * c + 4 * q];
#pragma unroll
                for (int r = 0; r < 4; r++) {
                    float v = sa[c][r] * SCL;
                    if ((&mv4.x)[r] == 0) v = -1e30f;
                    sc[c][r] = v;
                }
            }
        }
        // ---- tree max (exact; fmax associative) + cross-quad reduce ----
        float mx = fmaxf(
            fmaxf(fmaxf(fmaxf(sc[0][0], sc[0][1]), fmaxf(sc[0][2], sc[0][3])),
                  fmaxf(fmaxf(sc[1][0], sc[1][1]), fmaxf(sc[1][2], sc[1][3]))),
            fmaxf(fmaxf(fmaxf(sc[2][0], sc[2][1]), fmaxf(sc[2][2], sc[2][3])),
                  fmaxf(fmaxf(sc[3][0], sc[3][1]), fmaxf(sc[3][2], sc[3][3]))));
        mx = fmaxf(mx, __shfl_xor(mx, 16));
        mx = fmaxf(mx, __shfl_xor(mx, 32));
        float mn = fmaxf(m_i, mx);
        // skip rescale when alpha==1 for ALL lanes (identity; THR=0, exact)
        if (!__all(mx <= m_i)) {
            float alpha = exp2f(m_i - mn);
            l_i *= alpha;
#pragma unroll
            for (int nt = 0; nt < 8; nt++) {
                Oacc[nt][0] *= alpha; Oacc[nt][1] *= alpha;
                Oacc[nt][2] *= alpha; Oacc[nt][3] *= alpha;
            }
        }
        m_i = mn;
        // ---- P = exp2(sc - mn); masked entries underflow to exactly 0 ----
        float ps = 0.f;
#pragma unroll
        for (int c = 0; c < 4; c++) {
            float p0 = exp2f(sc[c][0] - mn);
            float p1 = exp2f(sc[c][1] - mn);
            float p2 = exp2f(sc[c][2] - mn);
            float p3 = exp2f(sc[c][3] - mn);
            ps += (p0 + p1) + (p2 + p3);
            uint2 pk2;
            pk2.x = cvtpk(p0, p1);
            pk2.y = cvtpk(p2, p3);
            *(uint2*)(Ptw + l15 * PTL + 16 * c + 4 * q) = pk2;
        }
        ps += __shfl_xor(ps, 16);
        ps += __shfl_xor(ps, 32);
        l_i += ps;
        // ---- PV: O^T(128 d x 16 s) += V^T(LDS) @ P^T(wave LDS) ----
        bf16x8 pb[2];
#pragma unroll
        for (int kt = 0; kt < 2; kt++)
            pb[kt] = *(const bf16x8*)(Ptw + l15 * PTL + kt * 32 + q * 8);
        __builtin_amdgcn_s_setprio(1);
#pragma unroll
        for (int nt = 0; nt < 8; nt++) {
#pragma unroll
            for (int kt = 0; kt < 2; kt++) {
                bf16x8 vf = *(const bf16x8*)(Vt + vtidx(16 * nt + l15, kt * 4 + q));
                Oacc[nt] = __builtin_amdgcn_mfma_f32_16x16x32_bf16(vf, pb[kt], Oacc[nt], 0, 0, 0);
            }
        }
        __builtin_amdgcn_s_setprio(0);
        __syncthreads();   // protect Kt/Vt for next step
    }

    // ---- epilogue (intra-wave; O^T rows d = 16nt+4q+r, col s = l15) ----
    float lv = (l_i > 0.f) ? 1.f / l_i : 0.f;

    if (!partial) {
        ushort* orow = o_heads + (size_t)(b * SS + my_s) * 2048 + h * VD_D;
#pragma unroll
        for (int nt = 0; nt < 8; nt++) {
            ushort4 pk;
            pk.x = f2bf(Oacc[nt][0] * lv); pk.y = f2bf(Oacc[nt][1] * lv);
            pk.z = f2bf(Oacc[nt][2] * lv); pk.w = f2bf(Oacc[nt][3] * lv);
            *(ushort4*)(orow + 16 * nt + 4 * q) = pk;
        }
    } else {
        const int sp = (t0s != 0);
        const int p = bh * 26 + (qt - 19) * 2 + sp;
        const int rl = 16 * w + l15;
        ushort* prow = Opart + ((size_t)p * 64 + rl) * 128;
#pragma unroll
        for (int nt = 0; nt < 8; nt++) {
            ushort4 pk;
            pk.x = f2bf(Oacc[nt][0] * lv); pk.y = f2bf(Oacc[nt][1] * lv);
            pk.z = f2bf(Oacc[nt][2] * lv); pk.w = f2bf(Oacc[nt][3] * lv);
            *(ushort4*)(prow + 16 * nt + 4 * q) = pk;
        }
        if (lane < 16)
            mlbuf[p * 64 + rl] = make_float2(m_i, l_i);
    }
}

// ---------------------------------------------------------------------------
// Merge span0/span1 partials for qt>=19.  grid 416 (= 32bh x 13qt) x 256.
// ---------------------------------------------------------------------------
__launch_bounds__(256)
__global__ void attn_merge(const ushort* __restrict__ Opart, const float2* __restrict__ mlbuf,
                           ushort* __restrict__ o_heads)
{
    int bh = blockIdx.x & 31, qi = blockIdx.x >> 5;
    int b = bh >> 4, h = bh & 15;
    int qt = 19 + qi;
    int t = threadIdx.x;
    int row = t >> 2, dbase = (t & 3) * 32;
    int p0 = bh * 26 + qi * 2, p1 = p0 + 1;
    float2 ml0 = mlbuf[p0 * 64 + row], ml1 = mlbuf[p1 * 64 + row];
    float M = fmaxf(ml0.x, ml1.x);
    float w0 = (ml0.y > 0.f) ? exp2f(ml0.x - M) * ml0.y : 0.f;
    float w1 = (ml1.y > 0.f) ? exp2f(ml1.x - M) * ml1.y : 0.f;
    float den = w0 + w1;
    float inv = (den > 0.f) ? 1.f / den : 0.f;
    w0 *= inv; w1 *= inv;
    int s = qt * 64 + row;
    const ushort* O0 = Opart + ((size_t)p0 * 64 + row) * 128 + dbase;
    const ushort* O1 = Opart + ((size_t)p1 * 64 + row) * 128 + dbase;
    ushort* dst = o_heads + (size_t)(b * SS + s) * 2048 + h * VD_D + dbase;
#pragma unroll
    for (int c = 0; c < 32; c += 8) {
        bf16x8 a = *(const bf16x8*)(O0 + c);
        bf16x8 bb = *(const bf16x8*)(O1 + c);
        bf16x8 o;
#pragma unroll
        for (int j = 0; j < 8; j++)
            o[j] = (short)f2bf(w0 * bf2f((unsigned short)a[j]) + w1 * bf2f((unsigned short)bb[j]));
        *(bf16x8*)(dst + c) = o;
    }
}

extern "C" void kernel_launch(void* const* d_in, const int* in_sizes, int n_in,
                              void* d_out, int out_size, void* d_ws, size_t ws_size,
                              hipStream_t stream)
{
    const float* x        = (const float*)d_in[0];
    const int*   mask     = (const int*)d_in[1];
    const float* wq_a_w   = (const float*)d_in[2];
    const float* wq_a_b   = (const float*)d_in[3];
    const float* q_norm_w = (const float*)d_in[4];
    const float* wq_b_w   = (const float*)d_in[5];
    const float* wq_b_b   = (const float*)d_in[6];
    const float* wkv_a_w  = (const float*)d_in[7];
    const float* wkv_a_b  = (const float*)d_in[8];
    const float* kv_norm_w= (const float*)d_in[9];
    const float* wkv_b_w  = (const float*)d_in[10];
    const float* wo_w     = (const float*)d_in[11];
    const float* wo_b     = (const float*)d_in[12];
    float* out = (float*)d_out;

    // Workspace (peak 102,662,144 B) — layout identical to R0
    char* W = (char*)d_ws;
    ushort* wo_bf    = (ushort*)(W + 0);
    ushort* qbuf     = (ushort*)(W + 8388608);
    ushort* wq_b_bf  = (ushort*)(W + 33554432);
    ushort* Kf       = (ushort*)(W + 33554432);
    ushort* wq_a_bf  = (ushort*)(W + 42991616);
    ushort* kvfull_bf= (ushort*)(W + 42991616);
    ushort* x_bf     = (ushort*)(W + 50331648);
    ushort* VT       = (ushort*)(W + 50331648);
    ushort* q_a_bf   = (ushort*)(W + 67108864);
    ushort* o_heads  = (ushort*)(W + 67108864);
    ushort* wkv_a_bf = (ushort*)(W + 79691776);
    ushort* wkv_b_bf = (ushort*)(W + 83886080);
    ushort* Opart    = (ushort*)(W + 83886080);
    float2* mlbuf    = (float2*)(W + 97517568);
    ushort* kvbf     = (ushort*)(W + 97943552);

    // 0. all f32->bf16 converts, one launch
    conv6<<<4096, 256, 0, stream>>>(
        x, x_bf, MROWS * HH / 4,
        wq_a_w, wq_a_bf, QLL * HH / 4,
        wq_b_w, wq_b_bf, 3072 * QLL / 4,
        wkv_a_w, wkv_a_bf, 576 * HH / 4,
        wkv_b_w, wkv_b_bf, NHH * 256 * 512 / 4,
        wo_w, wo_bf, HH * 2048 / 4);

    // 1. q_a = x @ wq_a^T + b  -> bf16
    gemm_bf<ushort><<<dim3(QLL/128, MROWS/128, 1), 256, 0, stream>>>(
        x_bf, HH, 0, 0, wq_a_bf, HH, 0, 0, wq_a_b, q_a_bf, QLL, 0, 0, MROWS, QLL, HH);
    // 2. rms_norm in place (bf16)
    rmsnorm_bf16<<<MROWS, 256, 0, stream>>>(q_a_bf, q_norm_w, QLL);
    // 3. q = q_a @ wq_b^T + b -> qbuf bf16
    gemm_bf<ushort><<<dim3(3072/128, MROWS/128, 1), 256, 0, stream>>>(
        q_a_bf, QLL, 0, 0, wq_b_bf, QLL, 0, 0, wq_b_b, qbuf, 3072, 0, 0, MROWS, 3072, QLL);
    // 4. kv_full = x @ wkv_a^T + b -> bf16 (N=576 guarded)
    gemm_bf<ushort><<<dim3(5, MROWS/128, 1), 256, 0, stream>>>(
        x_bf, HH, 0, 0, wkv_a_bf, HH, 0, 0, wkv_a_b, kvfull_bf, 576, 0, 0, MROWS, 576, HH);
    // 5. finalize kv (rms + rope) -> kvbf
    finalize_kv<<<MROWS, 256, 0, stream>>>(kvfull_bf, kv_norm_w, kvbf);
    // 6. rope q_pe in place on qbuf
    rope_q_kernel<<<dim3(MROWS, 4), 256, 0, stream>>>(qbuf);
    // 7. Kf[b,h] = kv_lat @ W_UK[h]^T  (nope only; M=2048,N=128,K=512, z=32)
    gemm_bf<ushort><<<dim3(1, SS/128, 32), 256, 0, stream>>>(
        kvbf, 576, (size_t)SS * 576, 0,
        wkv_b_bf, 512, 0, (size_t)256 * 512,
        nullptr, Kf, NOPE_D, (size_t)NHH * SS * NOPE_D, (size_t)SS * NOPE_D,
        SS, NOPE_D, 512);
    // 9. VT[b,h] = W_UV[h] @ kv_lat^T  (M=128,N=2048,K=512, z=32)
    gemm_bf<ushort><<<dim3(SS/128, 1, 32), 256, 0, stream>>>(
        wkv_b_bf + (size_t)128 * 512, 512, 0, (size_t)256 * 512,
        kvbf, 576, (size_t)SS * 576, 0,
        nullptr, VT, SS, (size_t)NHH * VD_D * SS, (size_t)VD_D * SS,
        VD_D, SS, 512);
    // 10. split-K MFMA flash attention (1440 blocks) + merge
    attn_mfma<<<NJOB * 32, 256, 0, stream>>>(qbuf, Kf, kvbf, VT, mask, o_heads, Opart, mlbuf);
    attn_merge<<<13 * 32, 256, 0, stream>>>(Opart, mlbuf, o_heads);
    // 12. out = o_heads @ wo^T + b
    gemm_bf<float><<<dim3(HH/128, MROWS/128, 1), 256, 0, stream>>>(
        o_heads, NHH * VD_D, 0, 0, wo_bf, NHH * VD_D, 0, 0, wo_b, out, HH, 0, 0,
        MROWS, HH, NHH * VD_D);
}

// Round 6
// 474.885 us; speedup vs baseline: 1.1672x; 1.0065x over previous
//
#include <hip/hip_runtime.h>
#include <hip/hip_bf16.h>

#define BB   2
#define SS   2048
#define HH   2048
#define NHH  16
#define QLL  1536
#define KVLL 512
#define NOPE_D 128
#define ROPE_D 64
#define QKH_D  192
#define VD_D   128
#define MROWS  (BB*SS)           // 4096 token rows

typedef __attribute__((ext_vector_type(8))) short bf16x8;   // 8 bf16 (4 VGPRs)
typedef __attribute__((ext_vector_type(4))) float f32x4;    // MFMA accumulator

__device__ inline float bf2f(unsigned short u) {
    union { float f; unsigned int i; } v; v.i = ((unsigned int)u) << 16; return v.f;
}
__device__ inline unsigned short f2bf(float f) {
    union { float f; unsigned int u; } v; v.f = f;
    unsigned int r = v.u + 0x7fffu + ((v.u >> 16) & 1u);
    return (unsigned short)(r >> 16);
}
// HW packed f32->bf16 (RNE): dst.lo = bf16(src0), dst.hi = bf16(src1)
__device__ __forceinline__ unsigned int cvtpk(float lo, float hi) {
    unsigned int r;
    asm("v_cvt_pk_bf16_f32 %0, %1, %2" : "=v"(r) : "v"(lo), "v"(hi));
    return r;
}

// async global->LDS, 16 B per lane.  LDS dest = wave-uniform base + lane*16.
__device__ __forceinline__ void gload_lds16(const ushort* g, ushort* l)
{
    __builtin_amdgcn_global_load_lds(
        (const __attribute__((address_space(1))) void*)(g),
        (__attribute__((address_space(3))) void*)(l), 16, 0, 0);
}

// ---------------------------------------------------------------------------
// One-launch f32 -> bf16 convert of all 6 tensors.
// ---------------------------------------------------------------------------
__global__ void conv6(const float* s0, ushort* d0, int n0,
                      const float* s1, ushort* d1, int n1,
                      const float* s2, ushort* d2, int n2,
                      const float* s3, ushort* d3, int n3,
                      const float* s4, ushort* d4, int n4,
                      const float* s5, ushort* d5, int n5)
{
    const int st = gridDim.x * 256;
    const int t0 = blockIdx.x * 256 + threadIdx.x;
    for (int i = t0; i < n0; i += st) { float4 v = ((const float4*)s0)[i]; ushort4 u; u.x=f2bf(v.x);u.y=f2bf(v.y);u.z=f2bf(v.z);u.w=f2bf(v.w); ((ushort4*)d0)[i]=u; }
    for (int i = t0; i < n1; i += st) { float4 v = ((const float4*)s1)[i]; ushort4 u; u.x=f2bf(v.x);u.y=f2bf(v.y);u.z=f2bf(v.z);u.w=f2bf(v.w); ((ushort4*)d1)[i]=u; }
    for (int i = t0; i < n2; i += st) { float4 v = ((const float4*)s2)[i]; ushort4 u; u.x=f2bf(v.x);u.y=f2bf(v.y);u.z=f2bf(v.z);u.w=f2bf(v.w); ((ushort4*)d2)[i]=u; }
    for (int i = t0; i < n3; i += st) { float4 v = ((const float4*)s3)[i]; ushort4 u; u.x=f2bf(v.x);u.y=f2bf(v.y);u.z=f2bf(v.z);u.w=f2bf(v.w); ((ushort4*)d3)[i]=u; }
    for (int i = t0; i < n4; i += st) { float4 v = ((const float4*)s4)[i]; ushort4 u; u.x=f2bf(v.x);u.y=f2bf(v.y);u.z=f2bf(v.z);u.w=f2bf(v.w); ((ushort4*)d4)[i]=u; }
    for (int i = t0; i < n5; i += st) { float4 v = ((const float4*)s5)[i]; ushort4 u; u.x=f2bf(v.x);u.y=f2bf(v.y);u.z=f2bf(v.z);u.w=f2bf(v.w); ((ushort4*)d5)[i]=u; }
}

// ---------------------------------------------------------------------------
// All-bf16 MFMA NT GEMM: 128x128 tile, BK=64, coalesced swizzled
// global_load_lds staging.  M mult of 128; N guarded; K mult of 64.
// NOTE (R4 lesson): no XCD blockIdx swizzle — operands are L3-resident at
// these sizes and the swizzle measured ~+7 us net (m160-consistent).
// ---------------------------------------------------------------------------
template<typename TC>
__launch_bounds__(256, 3)
__global__ void gemm_bf(const ushort* __restrict__ A, int lda, size_t Ab, size_t Ah,
                        const ushort* __restrict__ B, int ldb, size_t Bb, size_t Bh,
                        const float* __restrict__ bias,
                        TC* __restrict__ C, int ldc, size_t Cb, size_t Ch,
                        int M, int N, int K)
{
    __shared__ ushort As[128 * 64];
    __shared__ ushort Bs[128 * 64];
    const int z = blockIdx.z, bz = z >> 4, hz = z & 15;
    A += (size_t)bz * Ab + (size_t)hz * Ah;
    B += (size_t)bz * Bb + (size_t)hz * Bh;
    C += (size_t)bz * Cb + (size_t)hz * Ch;
    const int m0 = blockIdx.y * 128, n0 = blockIdx.x * 128;
    const int tid = threadIdx.x, w = tid >> 6, lane = tid & 63;
    const int l15 = lane & 15, q = lane >> 4;
    const int r7 = lane >> 3, c7 = lane & 7;
    const int xork = l15 & 7;

    f32x4 acc[4][4];
#pragma unroll
    for (int i = 0; i < 4; i++)
#pragma unroll
        for (int j = 0; j < 4; j++) acc[i][j] = (f32x4){0.f, 0.f, 0.f, 0.f};

    const int mrow = 64 * (w & 1) + l15;
    const int nrow = 64 * (w >> 1) + l15;

    for (int k0 = 0; k0 < K; k0 += 64) {
#pragma unroll
        for (int i = 0; i < 4; i++) {
            int g = 4 * w + i;
            int row = g * 8 + r7;
            int ch = c7 ^ r7;
            gload_lds16(A + (size_t)(m0 + row) * lda + k0 + ch * 8,
                        As + g * 512 + lane * 8);
            int rb = n0 + row; if (rb > N - 1) rb = N - 1;
            gload_lds16(B + (size_t)rb * ldb + k0 + ch * 8,
                        Bs + g * 512 + lane * 8);
        }
        __syncthreads();
#pragma unroll
        for (int ks = 0; ks < 2; ks++) {
            bf16x8 af[4], bf[4];
            const int chx = (ks * 4 + q) ^ xork;
#pragma unroll
            for (int mt = 0; mt < 4; mt++)
                af[mt] = *(const bf16x8*)(As + (mrow + 16 * mt) * 64 + chx * 8);
#pragma unroll
            for (int nt = 0; nt < 4; nt++)
                bf[nt] = *(const bf16x8*)(Bs + (nrow + 16 * nt) * 64 + chx * 8);
#pragma unroll
            for (int mt = 0; mt < 4; mt++)
#pragma unroll
                for (int nt = 0; nt < 4; nt++)
                    acc[mt][nt] = __builtin_amdgcn_mfma_f32_16x16x32_bf16(af[mt], bf[nt], acc[mt][nt], 0, 0, 0);
        }
        __syncthreads();
    }

#pragma unroll
    for (int nt = 0; nt < 4; nt++) {
        int n = n0 + nrow + 16 * nt;
        if (n >= N) continue;
        float bv = bias ? bias[n] : 0.f;
#pragma unroll
        for (int mt = 0; mt < 4; mt++) {
#pragma unroll
            for (int r = 0; r < 4; r++) {
                int m = m0 + 64 * (w & 1) + 16 * mt + 4 * q + r;
                float v = acc[mt][nt][r] + bv;
                if constexpr (sizeof(TC) == 2) C[(size_t)m * ldc + n] = f2bf(v);
                else                           C[(size_t)m * ldc + n] = v;
            }
        }
    }
}

// ---------------------------------------------------------------------------
// RMSNorm bf16 in-place, vectorized (ushort4 / float4).  width mult of 4.
// ---------------------------------------------------------------------------
__launch_bounds__(256)
__global__ void rmsnorm_bf16(ushort* __restrict__ x, const float* __restrict__ w, int width)
{
    ushort* xr = x + (size_t)blockIdx.x * width;
    const int w4 = width >> 2;
    float ss = 0.f;
    for (int i = threadIdx.x; i < w4; i += 256) {
        ushort4 v = ((const ushort4*)xr)[i];
        float a = bf2f(v.x), b = bf2f(v.y), c = bf2f(v.z), d = bf2f(v.w);
        ss += (a * a + b * b) + (c * c + d * d);
    }
    __shared__ float red[256];
    red[threadIdx.x] = ss; __syncthreads();
    for (int off = 128; off > 0; off >>= 1) {
        if (threadIdx.x < off) red[threadIdx.x] += red[threadIdx.x + off];
        __syncthreads();
    }
    float r = rsqrtf(red[0] / (float)width + 1e-6f);
    for (int i = threadIdx.x; i < w4; i += 256) {
        ushort4 v = ((const ushort4*)xr)[i];
        float4 wv = ((const float4*)w)[i];
        ushort4 o;
        o.x = f2bf(wv.x * bf2f(v.x) * r);
        o.y = f2bf(wv.y * bf2f(v.y) * r);
        o.z = f2bf(wv.z * bf2f(v.z) * r);
        o.w = f2bf(wv.w * bf2f(v.w) * r);
        ((ushort4*)xr)[i] = o;
    }
}

__device__ inline float rope_val(float xj, float xo, int j, int s)
{
    int i = j & 31;
    float freq = powf(10000.f, -(float)i / 32.f);
    float a = (float)s * freq;
    float sn, cs; sincosf(a, &sn, &cs);
    float other = (j < 32) ? -xo : xo;
    return xj * cs + other * sn;
}

// kv finalize: rms_norm latent 512 + rope pe 64, bf16 in -> kvbf bf16
__launch_bounds__(256)
__global__ void finalize_kv(const ushort* __restrict__ kvf, const float* __restrict__ w,
                            ushort* __restrict__ kvbf)
{
    int m = blockIdx.x, s = m & (SS - 1);
    const ushort* xr = kvf + (size_t)m * 576;
    float ss = 0.f;
    for (int i = threadIdx.x; i < 128; i += 256) {
        ushort4 v = ((const ushort4*)xr)[i];
        float a = bf2f(v.x), b = bf2f(v.y), c = bf2f(v.z), d = bf2f(v.w);
        ss += (a * a + b * b) + (c * c + d * d);
    }
    __shared__ float red[256];
    red[threadIdx.x] = ss; __syncthreads();
    for (int off = 128; off > 0; off >>= 1) {
        if (threadIdx.x < off) red[threadIdx.x] += red[threadIdx.x + off];
        __syncthreads();
    }
    float r = rsqrtf(red[0] / 512.f + 1e-6f);
    ushort* dr = kvbf + (size_t)m * 576;
    for (int i = threadIdx.x; i < 128; i += 256) {
        ushort4 v = ((const ushort4*)xr)[i];
        float4 wv = ((const float4*)w)[i];
        ushort4 o;
        o.x = f2bf(wv.x * bf2f(v.x) * r);
        o.y = f2bf(wv.y * bf2f(v.y) * r);
        o.z = f2bf(wv.z * bf2f(v.z) * r);
        o.w = f2bf(wv.w * bf2f(v.w) * r);
        ((ushort4*)dr)[i] = o;
    }
    if (threadIdx.x < 64) {
        int j = threadIdx.x;
        float xj = bf2f(xr[512 + j]), xo = bf2f(xr[512 + (j ^ 32)]);
        dr[512 + j] = f2bf(rope_val(xj, xo, j, s));
    }
}

// RoPE q_pe in place on qbuf bf16.  grid (4096,4) x 256; wave owns one head.
__global__ void rope_q_kernel(ushort* __restrict__ qbuf)
{
    int m = blockIdx.x, s = m & (SS - 1);
    int w = threadIdx.x >> 6, j = threadIdx.x & 63;
    int h = blockIdx.y * 4 + w;
    ushort* p = qbuf + (size_t)m * 3072 + h * QKH_D + NOPE_D;
    float xj = bf2f(p[j]);
    float xo = bf2f(p[j ^ 32]);
    p[j] = f2bf(rope_val(xj, xo, j, s));
}

// ---------------------------------------------------------------------------
// MFMA flash attention — R5 base + R6 K-tile prefetch:
//   3-barrier loop (skeleton refcheck'd in R3):
//     [1] tiles ready -> QK -> [2] (Kt dead) -> issue stageK(st+1) ->
//     softmax+PV (K-load latency hides here) -> [3] (Vt dead) -> stageV(st+1)
//   Kt is single-buffered: safe because all QK reads finish at [2] and the
//   prefetch writes complete+visible at the next [1] (barrier's vmcnt drain).
// NOTE (R3 lesson): keep 3 blocks/CU — 4/CU blows the per-XCD L2 working
// set (FETCH 48->139 MB).  NOTE (R1/R2 lesson): shuffle-P stays dead.
// ---------------------------------------------------------------------------
#define SCL  0.10411760f  // (1/sqrt(192)) * log2(e)
#define PTL  72
#define NJOB 45

__constant__ unsigned char JQT[NJOB] = {18,17,16,19,20,21,22,23,24,25,26,27,28,29,30,31,15,31,14,30,13,29,12,28,11,27,10,26,9,25,8,24,7,23,6,22,5,21,4,20,3,19,2,1,0};
__constant__ unsigned char JT0[NJOB] = { 0, 0, 0, 0, 0, 0, 0, 0, 0, 0, 0, 0, 0, 0, 0, 0, 0,16, 0,16, 0,16, 0,16, 0,16, 0,16, 0,16, 0,16, 0,16, 0,16, 0,16, 0,16, 0,16, 0, 0, 0};
__constant__ unsigned char JT1[NJOB] = {19,18,17,16,16,16,16,16,16,16,16,16,16,16,16,16,16,32,15,31,14,30,13,29,12,28,11,27,10,26, 9,25, 8,24, 7,23, 6,22, 5,21, 4,20, 3, 2, 1};

__device__ __forceinline__ int ktidx(int row, int ch) {
    return (((ch >> 3) << 3) + (row >> 3)) * 512 + (row & 7) * 64 + (((ch & 7) ^ (row & 7)) << 3);
}
// Vt: 16 groups of 8 d-rows; slot swizzle chunk^(d&7)
__device__ __forceinline__ int vtidx(int d, int ch) {
    return (d >> 3) * 512 + (d & 7) * 64 + ((ch ^ (d & 7)) << 3);
}

__launch_bounds__(256, 3)
__global__ void attn_mfma(const ushort* __restrict__ qbuf, const ushort* __restrict__ Kf,
                          const ushort* __restrict__ kvbf, const ushort* __restrict__ VT,
                          const int* __restrict__ mask, ushort* __restrict__ o_heads,
                          ushort* __restrict__ Opart, float2* __restrict__ mlbuf)
{
    __shared__ ushort Kt[24 * 512];      // 24,576 B shared K-tile (64 t x 192)
    __shared__ ushort Vt[16 * 512];      // 16,384 B shared V^T tile (128 d x 64 t)
    __shared__ ushort Pt[4 * 16 * PTL];  //  9,216 B wave-private P^T slabs

    const int tid = threadIdx.x, w = tid >> 6, lane = tid & 63;
    const int l15 = lane & 15, q = lane >> 4;
    const int r7 = lane >> 3, c7 = lane & 7;

    const int job = blockIdx.x >> 5, bh = blockIdx.x & 31;
    const int b = bh >> 4, h = bh & 15;
    const int qt = JQT[job], t0s = JT0[job], t1s = JT1[job];
    const int s0 = qt * 64;
    const bool partial = (t0s != 0) | (t1s != qt + 1);

    const ushort* Kf_bh = Kf + (size_t)bh * SS * NOPE_D;
    const ushort* VT_bh = VT + (size_t)bh * VD_D * SS;
    const ushort* kpe_b = kvbf + (size_t)b * SS * 576 + 512;
    const int* mrow = mask + b * SS;
    ushort* Ptw = Pt + w * 16 * PTL;

    // Q B-frags: rows s0+16w..+15 (n = lane&15), 6 k-chunks of 32 over 192 dims
    bf16x8 qf[6];
    {
        const ushort* qbase = qbuf + ((size_t)(b * SS) + s0 + 16 * w + l15) * 3072 + h * QKH_D + q * 8;
#pragma unroll
        for (int k = 0; k < 6; k++) qf[k] = *(const bf16x8*)(qbase + k * 32);
    }

    f32x4 Oacc[8];   // O^T: rows d = 16nt+4q+r, col s = l15
#pragma unroll
    for (int nt = 0; nt < 8; nt++) Oacc[nt] = (f32x4){0.f, 0.f, 0.f, 0.f};
    float m_i = -3e38f, l_i = 0.f;
    const int my_s = s0 + 16 * w + l15;

    auto stageK = [&](int t0) {
#pragma unroll
        for (int i = 0; i < 6; i++) {
            int g = 6 * w + i;
            int rg = g & 7, cg = g >> 3;
            int row = rg * 8 + r7;
            int chl = c7 ^ r7;
            const ushort* src = (cg < 2)
                ? Kf_bh + (size_t)(t0 + row) * NOPE_D + (cg * 8 + chl) * 8
                : kpe_b + (size_t)(t0 + row) * 576 + chl * 8;
            gload_lds16(src, Kt + g * 512 + lane * 8);
        }
    };
    auto stageV = [&](int t0) {
#pragma unroll
        for (int i = 0; i < 4; i++) {
            int g = 4 * w + i;                  // d-group 0..15
            int d = g * 8 + r7;
            gload_lds16(VT_bh + (size_t)d * SS + t0 + ((c7 ^ r7) << 3),
                        Vt + g * 512 + lane * 8);
        }
    };

    // prologue: stage first K and V tiles
    stageK(t0s * 64);
    stageV(t0s * 64);

    for (int st = t0s; st < t1s; st++) {
        const int t0 = st * 64;
        __syncthreads();                         // [1] tiles staged+visible
        // ---- scores S^T(64 t x 16 s): sa[c] rows t=16c+4q+r, col s=l15 ----
        f32x4 sa[4];
#pragma unroll
        for (int c = 0; c < 4; c++) sa[c] = (f32x4){0.f, 0.f, 0.f, 0.f};
        __builtin_amdgcn_s_setprio(1);
#pragma unroll
        for (int k = 0; k < 6; k++) {
#pragma unroll
            for (int c = 0; c < 4; c++) {
                bf16x8 kb = *(const bf16x8*)(Kt + ktidx(16 * c + l15, 4 * k + q));
                sa[c] = __builtin_amdgcn_mfma_f32_16x16x32_bf16(kb, qf[k], sa[c], 0, 0, 0);
            }
        }
        __builtin_amdgcn_s_setprio(0);
        __syncthreads();                         // [2] all QK reads of Kt done
        // Kt dead until next [1]: prefetch next K-tile; latency hides under
        // softmax + PV, completion enforced by next [1]'s vmcnt drain.
        if (st + 1 < t1s) stageK(t0 + 64);
        // ---- masked scores: causal only on the diagonal tile (st==qt) ----
        float sc[4][4];
        if (st == qt) {
#pragma unroll
            for (int c = 0; c < 4; c++) {
                int4 mv4 = *(const int4*)&mrow[t0 + 16 * c + 4 * q];
#pragma unroll
                for (int r = 0; r < 4; r++) {
                    int t = t0 + 16 * c + 4 * q + r;
                    float v = sa[c][r] * SCL;
                    if (t > my_s || (&mv4.x)[r] == 0) v = -1e30f;
                    sc[c][r] = v;
                }
            }
        } else {
#pragma unroll
            for (int c = 0; c < 4; c++) {
                int4 mv4 = *(const int4*)&mrow[t0 + 16 * c + 4 * q];
#pragma unroll
                for (int r = 0; r < 4; r++) {
                    float v = sa[c][r] * SCL;
                    if ((&mv4.x)[r] == 0) v = -1e30f;
                    sc[c][r] = v;
                }
            }
        }
        // ---- tree max (exact; fmax associative) + cross-quad reduce ----
        float mx = fmaxf(
            fmaxf(fmaxf(fmaxf(sc[0][0], sc[0][1]), fmaxf(sc[0][2], sc[0][3])),
                  fmaxf(fmaxf(sc[1][0], sc[1][1]), fmaxf(sc[1][2], sc[1][3]))),
            fmaxf(fmaxf(fmaxf(sc[2][0], sc[2][1]), fmaxf(sc[2][2], sc[2][3])),
                  fmaxf(fmaxf(sc[3][0], sc[3][1]), fmaxf(sc[3][2], sc[3][3]))));
        mx = fmaxf(mx, __shfl_xor(mx, 16));
        mx = fmaxf(mx, __shfl_xor(mx, 32));
        float mn = fmaxf(m_i, mx);
        // skip rescale when alpha==1 for ALL lanes (identity; THR=0, exact)
        if (!__all(mx <= m_i)) {
            float alpha = exp2f(m_i - mn);
            l_i *= alpha;
#pragma unroll
            for (int nt = 0; nt < 8; nt++) {
                Oacc[nt][0] *= alpha; Oacc[nt][1] *= alpha;
                Oacc[nt][2] *= alpha; Oacc[nt][3] *= alpha;
            }
        }
        m_i = mn;
        // ---- P = exp2(sc - mn); masked entries underflow to exactly 0 ----
        float ps = 0.f;
#pragma unroll
        for (int c = 0; c < 4; c++) {
            float p0 = exp2f(sc[c][0] - mn);
            float p1 = exp2f(sc[c][1] - mn);
            float p2 = exp2f(sc[c][2] - mn);
            float p3 = exp2f(sc[c][3] - mn);
            ps += (p0 + p1) + (p2 + p3);
            uint2 pk2;
            pk2.x = cvtpk(p0, p1);
            pk2.y = cvtpk(p2, p3);
            *(uint2*)(Ptw + l15 * PTL + 16 * c + 4 * q) = pk2;
        }
        ps += __shfl_xor(ps, 16);
        ps += __shfl_xor(ps, 32);
        l_i += ps;
        // ---- PV: O^T(128 d x 16 s) += V^T(LDS) @ P^T(wave LDS) ----
        bf16x8 pb[2];
#pragma unroll
        for (int kt = 0; kt < 2; kt++)
            pb[kt] = *(const bf16x8*)(Ptw + l15 * PTL + kt * 32 + q * 8);
        __builtin_amdgcn_s_setprio(1);
#pragma unroll
        for (int nt = 0; nt < 8; nt++) {
#pragma unroll
            for (int kt = 0; kt < 2; kt++) {
                bf16x8 vf = *(const bf16x8*)(Vt + vtidx(16 * nt + l15, kt * 4 + q));
                Oacc[nt] = __builtin_amdgcn_mfma_f32_16x16x32_bf16(vf, pb[kt], Oacc[nt], 0, 0, 0);
            }
        }
        __builtin_amdgcn_s_setprio(0);
        __syncthreads();                         // [3] Vt reads done
        if (st + 1 < t1s) stageV(t0 + 64);       // stage next V-tile
    }

    // ---- epilogue (intra-wave; O^T rows d = 16nt+4q+r, col s = l15) ----
    float lv = (l_i > 0.f) ? 1.f / l_i : 0.f;

    if (!partial) {
        ushort* orow = o_heads + (size_t)(b * SS + my_s) * 2048 + h * VD_D;
#pragma unroll
        for (int nt = 0; nt < 8; nt++) {
            ushort4 pk;
            pk.x = f2bf(Oacc[nt][0] * lv); pk.y = f2bf(Oacc[nt][1] * lv);
            pk.z = f2bf(Oacc[nt][2] * lv); pk.w = f2bf(Oacc[nt][3] * lv);
            *(ushort4*)(orow + 16 * nt + 4 * q) = pk;
        }
    } else {
        const int sp = (t0s != 0);
        const int p = bh * 26 + (qt - 19) * 2 + sp;
        const int rl = 16 * w + l15;
        ushort* prow = Opart + ((size_t)p * 64 + rl) * 128;
#pragma unroll
        for (int nt = 0; nt < 8; nt++) {
            ushort4 pk;
            pk.x = f2bf(Oacc[nt][0] * lv); pk.y = f2bf(Oacc[nt][1] * lv);
            pk.z = f2bf(Oacc[nt][2] * lv); pk.w = f2bf(Oacc[nt][3] * lv);
            *(ushort4*)(prow + 16 * nt + 4 * q) = pk;
        }
        if (lane < 16)
            mlbuf[p * 64 + rl] = make_float2(m_i, l_i);
    }
}

// ---------------------------------------------------------------------------
// Merge span0/span1 partials for qt>=19.  grid 416 (= 32bh x 13qt) x 256.
// ---------------------------------------------------------------------------
__launch_bounds__(256)
__global__ void attn_merge(const ushort* __restrict__ Opart, const float2* __restrict__ mlbuf,
                           ushort* __restrict__ o_heads)
{
    int bh = blockIdx.x & 31, qi = blockIdx.x >> 5;
    int b = bh >> 4, h = bh & 15;
    int qt = 19 + qi;
    int t = threadIdx.x;
    int row = t >> 2, dbase = (t & 3) * 32;
    int p0 = bh * 26 + qi * 2, p1 = p0 + 1;
    float2 ml0 = mlbuf[p0 * 64 + row], ml1 = mlbuf[p1 * 64 + row];
    float M = fmaxf(ml0.x, ml1.x);
    float w0 = (ml0.y > 0.f) ? exp2f(ml0.x - M) * ml0.y : 0.f;
    float w1 = (ml1.y > 0.f) ? exp2f(ml1.x - M) * ml1.y : 0.f;
    float den = w0 + w1;
    float inv = (den > 0.f) ? 1.f / den : 0.f;
    w0 *= inv; w1 *= inv;
    int s = qt * 64 + row;
    const ushort* O0 = Opart + ((size_t)p0 * 64 + row) * 128 + dbase;
    const ushort* O1 = Opart + ((size_t)p1 * 64 + row) * 128 + dbase;
    ushort* dst = o_heads + (size_t)(b * SS + s) * 2048 + h * VD_D + dbase;
#pragma unroll
    for (int c = 0; c < 32; c += 8) {
        bf16x8 a = *(const bf16x8*)(O0 + c);
        bf16x8 bb = *(const bf16x8*)(O1 + c);
        bf16x8 o;
#pragma unroll
        for (int j = 0; j < 8; j++)
            o[j] = (short)f2bf(w0 * bf2f((unsigned short)a[j]) + w1 * bf2f((unsigned short)bb[j]));
        *(bf16x8*)(dst + c) = o;
    }
}

extern "C" void kernel_launch(void* const* d_in, const int* in_sizes, int n_in,
                              void* d_out, int out_size, void* d_ws, size_t ws_size,
                              hipStream_t stream)
{
    const float* x        = (const float*)d_in[0];
    const int*   mask     = (const int*)d_in[1];
    const float* wq_a_w   = (const float*)d_in[2];
    const float* wq_a_b   = (const float*)d_in[3];
    const float* q_norm_w = (const float*)d_in[4];
    const float* wq_b_w   = (const float*)d_in[5];
    const float* wq_b_b   = (const float*)d_in[6];
    const float* wkv_a_w  = (const float*)d_in[7];
    const float* wkv_a_b  = (const float*)d_in[8];
    const float* kv_norm_w= (const float*)d_in[9];
    const float* wkv_b_w  = (const float*)d_in[10];
    const float* wo_w     = (const float*)d_in[11];
    const float* wo_b     = (const float*)d_in[12];
    float* out = (float*)d_out;

    // Workspace (peak 102,662,144 B) — layout identical to R0
    char* W = (char*)d_ws;
    ushort* wo_bf    = (ushort*)(W + 0);
    ushort* qbuf     = (ushort*)(W + 8388608);
    ushort* wq_b_bf  = (ushort*)(W + 33554432);
    ushort* Kf       = (ushort*)(W + 33554432);
    ushort* wq_a_bf  = (ushort*)(W + 42991616);
    ushort* kvfull_bf= (ushort*)(W + 42991616);
    ushort* x_bf     = (ushort*)(W + 50331648);
    ushort* VT       = (ushort*)(W + 50331648);
    ushort* q_a_bf   = (ushort*)(W + 67108864);
    ushort* o_heads  = (ushort*)(W + 67108864);
    ushort* wkv_a_bf = (ushort*)(W + 79691776);
    ushort* wkv_b_bf = (ushort*)(W + 83886080);
    ushort* Opart    = (ushort*)(W + 83886080);
    float2* mlbuf    = (float2*)(W + 97517568);
    ushort* kvbf     = (ushort*)(W + 97943552);

    // 0. all f32->bf16 converts, one launch
    conv6<<<4096, 256, 0, stream>>>(
        x, x_bf, MROWS * HH / 4,
        wq_a_w, wq_a_bf, QLL * HH / 4,
        wq_b_w, wq_b_bf, 3072 * QLL / 4,
        wkv_a_w, wkv_a_bf, 576 * HH / 4,
        wkv_b_w, wkv_b_bf, NHH * 256 * 512 / 4,
        wo_w, wo_bf, HH * 2048 / 4);

    // 1. q_a = x @ wq_a^T + b  -> bf16
    gemm_bf<ushort><<<dim3(QLL/128, MROWS/128, 1), 256, 0, stream>>>(
        x_bf, HH, 0, 0, wq_a_bf, HH, 0, 0, wq_a_b, q_a_bf, QLL, 0, 0, MROWS, QLL, HH);
    // 2. rms_norm in place (bf16)
    rmsnorm_bf16<<<MROWS, 256, 0, stream>>>(q_a_bf, q_norm_w, QLL);
    // 3. q = q_a @ wq_b^T + b -> qbuf bf16
    gemm_bf<ushort><<<dim3(3072/128, MROWS/128, 1), 256, 0, stream>>>(
        q_a_bf, QLL, 0, 0, wq_b_bf, QLL, 0, 0, wq_b_b, qbuf, 3072, 0, 0, MROWS, 3072, QLL);
    // 4. kv_full = x @ wkv_a^T + b -> bf16 (N=576 guarded)
    gemm_bf<ushort><<<dim3(5, MROWS/128, 1), 256, 0, stream>>>(
        x_bf, HH, 0, 0, wkv_a_bf, HH, 0, 0, wkv_a_b, kvfull_bf, 576, 0, 0, MROWS, 576, HH);
    // 5. finalize kv (rms + rope) -> kvbf
    finalize_kv<<<MROWS, 256, 0, stream>>>(kvfull_bf, kv_norm_w, kvbf);
    // 6. rope q_pe in place on qbuf
    rope_q_kernel<<<dim3(MROWS, 4), 256, 0, stream>>>(qbuf);
    // 7. Kf[b,h] = kv_lat @ W_UK[h]^T  (nope only; M=2048,N=128,K=512, z=32)
    gemm_bf<ushort><<<dim3(1, SS/128, 32), 256, 0, stream>>>(
        kvbf, 576, (size_t)SS * 576, 0,
        wkv_b_bf, 512, 0, (size_t)256 * 512,
        nullptr, Kf, NOPE_D, (size_t)NHH * SS * NOPE_D, (size_t)SS * NOPE_D,
        SS, NOPE_D, 512);
    // 9. VT[b,h] = W_UV[h] @ kv_lat^T  (M=128,N=2048,K=512, z=32)
    gemm_bf<ushort><<<dim3(SS/128, 1, 32), 256, 0, stream>>>(
        wkv_b_bf + (size_t)128 * 512, 512, 0, (size_t)256 * 512,
        kvbf, 576, (size_t)SS * 576, 0,
        nullptr, VT, SS, (size_t)NHH * VD_D * SS, (size_t)VD_D * SS,
        VD_D, SS, 512);
    // 10. split-K MFMA flash attention (1440 blocks) + merge
    attn_mfma<<<NJOB * 32, 256, 0, stream>>>(qbuf, Kf, kvbf, VT, mask, o_heads, Opart, mlbuf);
    attn_merge<<<13 * 32, 256, 0, stream>>>(Opart, mlbuf, o_heads);
    // 12. out = o_heads @ wo^T + b
    gemm_bf<float><<<dim3(HH/128, MROWS/128, 1), 256, 0, stream>>>(
        o_heads, NHH * VD_D, 0, 0, wo_bf, NHH * VD_D, 0, 0, wo_b, out, HH, 0, 0,
        MROWS, HH, NHH * VD_D);
}

// Round 7
// 442.952 us; speedup vs baseline: 1.2514x; 1.0721x over previous
//
#include <hip/hip_runtime.h>
#include <hip/hip_bf16.h>

#define BB   2
#define SS   2048
#define HH   2048
#define NHH  16
#define QLL  1536
#define KVLL 512
#define NOPE_D 128
#define ROPE_D 64
#define QKH_D  192
#define VD_D   128
#define MROWS  (BB*SS)           // 4096 token rows
#define NQKV  2112               // 1536 (q latent) + 576 (kv latent + pe)

typedef __attribute__((ext_vector_type(8))) short bf16x8;   // 8 bf16 (4 VGPRs)
typedef __attribute__((ext_vector_type(4))) float f32x4;    // MFMA accumulator

__device__ inline float bf2f(unsigned short u) {
    union { float f; unsigned int i; } v; v.i = ((unsigned int)u) << 16; return v.f;
}
__device__ inline unsigned short f2bf(float f) {
    union { float f; unsigned int u; } v; v.f = f;
    unsigned int r = v.u + 0x7fffu + ((v.u >> 16) & 1u);
    return (unsigned short)(r >> 16);
}
// HW packed f32->bf16 (RNE): dst.lo = bf16(src0), dst.hi = bf16(src1)
__device__ __forceinline__ unsigned int cvtpk(float lo, float hi) {
    unsigned int r;
    asm("v_cvt_pk_bf16_f32 %0, %1, %2" : "=v"(r) : "v"(lo), "v"(hi));
    return r;
}

// async global->LDS, 16 B per lane.  LDS dest = wave-uniform base + lane*16.
__device__ __forceinline__ void gload_lds16(const ushort* g, ushort* l)
{
    __builtin_amdgcn_global_load_lds(
        (const __attribute__((address_space(1))) void*)(g),
        (__attribute__((address_space(3))) void*)(l), 16, 0, 0);
}

// ---------------------------------------------------------------------------
// One-launch f32 -> bf16 convert of 6 tensor regions + combined bias build.
// Slot 1+2 write the CONCATENATED [wq_a; wkv_a] (2112 x 2048) weight.
// ---------------------------------------------------------------------------
__global__ void conv6(const float* s0, ushort* d0, int n0,
                      const float* s1, ushort* d1, int n1,
                      const float* s2, ushort* d2, int n2,
                      const float* s3, ushort* d3, int n3,
                      const float* s4, ushort* d4, int n4,
                      const float* s5, ushort* d5, int n5,
                      const float* b0, const float* b1, float* cb)
{
    const int st = gridDim.x * 256;
    const int t0 = blockIdx.x * 256 + threadIdx.x;
    for (int i = t0; i < n0; i += st) { float4 v = ((const float4*)s0)[i]; ushort4 u; u.x=f2bf(v.x);u.y=f2bf(v.y);u.z=f2bf(v.z);u.w=f2bf(v.w); ((ushort4*)d0)[i]=u; }
    for (int i = t0; i < n1; i += st) { float4 v = ((const float4*)s1)[i]; ushort4 u; u.x=f2bf(v.x);u.y=f2bf(v.y);u.z=f2bf(v.z);u.w=f2bf(v.w); ((ushort4*)d1)[i]=u; }
    for (int i = t0; i < n2; i += st) { float4 v = ((const float4*)s2)[i]; ushort4 u; u.x=f2bf(v.x);u.y=f2bf(v.y);u.z=f2bf(v.z);u.w=f2bf(v.w); ((ushort4*)d2)[i]=u; }
    for (int i = t0; i < n3; i += st) { float4 v = ((const float4*)s3)[i]; ushort4 u; u.x=f2bf(v.x);u.y=f2bf(v.y);u.z=f2bf(v.z);u.w=f2bf(v.w); ((ushort4*)d3)[i]=u; }
    for (int i = t0; i < n4; i += st) { float4 v = ((const float4*)s4)[i]; ushort4 u; u.x=f2bf(v.x);u.y=f2bf(v.y);u.z=f2bf(v.z);u.w=f2bf(v.w); ((ushort4*)d4)[i]=u; }
    for (int i = t0; i < n5; i += st) { float4 v = ((const float4*)s5)[i]; ushort4 u; u.x=f2bf(v.x);u.y=f2bf(v.y);u.z=f2bf(v.z);u.w=f2bf(v.w); ((ushort4*)d5)[i]=u; }
    for (int i = t0; i < NQKV; i += st)
        cb[i] = (i < QLL) ? b0[i] : b1[i - QLL];
}

// ---------------------------------------------------------------------------
// All-bf16 MFMA NT GEMM: 128x128 tile, BK=64, coalesced swizzled
// global_load_lds staging.  M mult of 128; N guarded; K mult of 64.
// NOTE (R4 lesson): no XCD blockIdx swizzle — operands are L3-resident at
// these sizes and the swizzle measured ~+7 us net (m160-consistent).
// ---------------------------------------------------------------------------
template<typename TC>
__launch_bounds__(256, 3)
__global__ void gemm_bf(const ushort* __restrict__ A, int lda, size_t Ab, size_t Ah,
                        const ushort* __restrict__ B, int ldb, size_t Bb, size_t Bh,
                        const float* __restrict__ bias,
                        TC* __restrict__ C, int ldc, size_t Cb, size_t Ch,
                        int M, int N, int K)
{
    __shared__ ushort As[128 * 64];
    __shared__ ushort Bs[128 * 64];
    const int z = blockIdx.z, bz = z >> 4, hz = z & 15;
    A += (size_t)bz * Ab + (size_t)hz * Ah;
    B += (size_t)bz * Bb + (size_t)hz * Bh;
    C += (size_t)bz * Cb + (size_t)hz * Ch;
    const int m0 = blockIdx.y * 128, n0 = blockIdx.x * 128;
    const int tid = threadIdx.x, w = tid >> 6, lane = tid & 63;
    const int l15 = lane & 15, q = lane >> 4;
    const int r7 = lane >> 3, c7 = lane & 7;
    const int xork = l15 & 7;

    f32x4 acc[4][4];
#pragma unroll
    for (int i = 0; i < 4; i++)
#pragma unroll
        for (int j = 0; j < 4; j++) acc[i][j] = (f32x4){0.f, 0.f, 0.f, 0.f};

    const int mrow = 64 * (w & 1) + l15;
    const int nrow = 64 * (w >> 1) + l15;

    for (int k0 = 0; k0 < K; k0 += 64) {
#pragma unroll
        for (int i = 0; i < 4; i++) {
            int g = 4 * w + i;
            int row = g * 8 + r7;
            int ch = c7 ^ r7;
            gload_lds16(A + (size_t)(m0 + row) * lda + k0 + ch * 8,
                        As + g * 512 + lane * 8);
            int rb = n0 + row; if (rb > N - 1) rb = N - 1;
            gload_lds16(B + (size_t)rb * ldb + k0 + ch * 8,
                        Bs + g * 512 + lane * 8);
        }
        __syncthreads();
#pragma unroll
        for (int ks = 0; ks < 2; ks++) {
            bf16x8 af[4], bf[4];
            const int chx = (ks * 4 + q) ^ xork;
#pragma unroll
            for (int mt = 0; mt < 4; mt++)
                af[mt] = *(const bf16x8*)(As + (mrow + 16 * mt) * 64 + chx * 8);
#pragma unroll
            for (int nt = 0; nt < 4; nt++)
                bf[nt] = *(const bf16x8*)(Bs + (nrow + 16 * nt) * 64 + chx * 8);
#pragma unroll
            for (int mt = 0; mt < 4; mt++)
#pragma unroll
                for (int nt = 0; nt < 4; nt++)
                    acc[mt][nt] = __builtin_amdgcn_mfma_f32_16x16x32_bf16(af[mt], bf[nt], acc[mt][nt], 0, 0, 0);
        }
        __syncthreads();
    }

#pragma unroll
    for (int nt = 0; nt < 4; nt++) {
        int n = n0 + nrow + 16 * nt;
        if (n >= N) continue;
        float bv = bias ? bias[n] : 0.f;
#pragma unroll
        for (int mt = 0; mt < 4; mt++) {
#pragma unroll
            for (int r = 0; r < 4; r++) {
                int m = m0 + 64 * (w & 1) + 16 * mt + 4 * q + r;
                float v = acc[mt][nt][r] + bv;
                if constexpr (sizeof(TC) == 2) C[(size_t)m * ldc + n] = f2bf(v);
                else                           C[(size_t)m * ldc + n] = v;
            }
        }
    }
}

// ---------------------------------------------------------------------------
// RMSNorm bf16 in-place, vectorized; row stride parameterized (width mult 4).
// ---------------------------------------------------------------------------
__launch_bounds__(256)
__global__ void rmsnorm_bf16(ushort* __restrict__ x, const float* __restrict__ w,
                             int width, int stride)
{
    ushort* xr = x + (size_t)blockIdx.x * stride;
    const int w4 = width >> 2;
    float ss = 0.f;
    for (int i = threadIdx.x; i < w4; i += 256) {
        ushort4 v = ((const ushort4*)xr)[i];
        float a = bf2f(v.x), b = bf2f(v.y), c = bf2f(v.z), d = bf2f(v.w);
        ss += (a * a + b * b) + (c * c + d * d);
    }
    __shared__ float red[256];
    red[threadIdx.x] = ss; __syncthreads();
    for (int off = 128; off > 0; off >>= 1) {
        if (threadIdx.x < off) red[threadIdx.x] += red[threadIdx.x + off];
        __syncthreads();
    }
    float r = rsqrtf(red[0] / (float)width + 1e-6f);
    for (int i = threadIdx.x; i < w4; i += 256) {
        ushort4 v = ((const ushort4*)xr)[i];
        float4 wv = ((const float4*)w)[i];
        ushort4 o;
        o.x = f2bf(wv.x * bf2f(v.x) * r);
        o.y = f2bf(wv.y * bf2f(v.y) * r);
        o.z = f2bf(wv.z * bf2f(v.z) * r);
        o.w = f2bf(wv.w * bf2f(v.w) * r);
        ((ushort4*)xr)[i] = o;
    }
}

__device__ inline float rope_val(float xj, float xo, int j, int s)
{
    int i = j & 31;
    float freq = powf(10000.f, -(float)i / 32.f);
    float a = (float)s * freq;
    float sn, cs; sincosf(a, &sn, &cs);
    float other = (j < 32) ? -xo : xo;
    return xj * cs + other * sn;
}

// kv finalize: reads kv part (cols 1536..2111) of qkv_a (stride NQKV);
// rms_norm latent 512 + rope pe 64 -> kvbf (stride 576).
__launch_bounds__(256)
__global__ void finalize_kv(const ushort* __restrict__ qkv, const float* __restrict__ w,
                            ushort* __restrict__ kvbf)
{
    int m = blockIdx.x, s = m & (SS - 1);
    const ushort* xr = qkv + (size_t)m * NQKV + QLL;
    float ss = 0.f;
    for (int i = threadIdx.x; i < 128; i += 256) {
        ushort4 v = ((const ushort4*)xr)[i];
        float a = bf2f(v.x), b = bf2f(v.y), c = bf2f(v.z), d = bf2f(v.w);
        ss += (a * a + b * b) + (c * c + d * d);
    }
    __shared__ float red[256];
    red[threadIdx.x] = ss; __syncthreads();
    for (int off = 128; off > 0; off >>= 1) {
        if (threadIdx.x < off) red[threadIdx.x] += red[threadIdx.x + off];
        __syncthreads();
    }
    float r = rsqrtf(red[0] / 512.f + 1e-6f);
    ushort* dr = kvbf + (size_t)m * 576;
    for (int i = threadIdx.x; i < 128; i += 256) {
        ushort4 v = ((const ushort4*)xr)[i];
        float4 wv = ((const float4*)w)[i];
        ushort4 o;
        o.x = f2bf(wv.x * bf2f(v.x) * r);
        o.y = f2bf(wv.y * bf2f(v.y) * r);
        o.z = f2bf(wv.z * bf2f(v.z) * r);
        o.w = f2bf(wv.w * bf2f(v.w) * r);
        ((ushort4*)dr)[i] = o;
    }
    if (threadIdx.x < 64) {
        int j = threadIdx.x;
        float xj = bf2f(xr[512 + j]), xo = bf2f(xr[512 + (j ^ 32)]);
        dr[512 + j] = f2bf(rope_val(xj, xo, j, s));
    }
}

// RoPE q_pe in place on qbuf bf16.  grid (4096,4) x 256; wave owns one head.
__global__ void rope_q_kernel(ushort* __restrict__ qbuf)
{
    int m = blockIdx.x, s = m & (SS - 1);
    int w = threadIdx.x >> 6, j = threadIdx.x & 63;
    int h = blockIdx.y * 4 + w;
    ushort* p = qbuf + (size_t)m * 3072 + h * QKH_D + NOPE_D;
    float xj = bf2f(p[j]);
    float xo = bf2f(p[j ^ 32]);
    p[j] = f2bf(rope_val(xj, xo, j, s));
}

// ---------------------------------------------------------------------------
// MFMA flash attention — R5 verified structure (2 barriers/step, Pt slab,
// 50,176 B LDS, 3 blocks/CU) + VALU diet (diag-hoist, tree-max, skip-rescale,
// cvtpk P-pack, setprio).  R6's 3-barrier prefetch reverted (measured
// neutral: hidden K latency == newly-exposed V latency + extra barrier).
// NOTE (R3): 4/CU blows per-XCD L2 (FETCH 48->139 MB).  Shuffle-P stays dead.
// ---------------------------------------------------------------------------
#define SCL  0.10411760f  // (1/sqrt(192)) * log2(e)
#define PTL  72
#define NJOB 45

__constant__ unsigned char JQT[NJOB] = {18,17,16,19,20,21,22,23,24,25,26,27,28,29,30,31,15,31,14,30,13,29,12,28,11,27,10,26,9,25,8,24,7,23,6,22,5,21,4,20,3,19,2,1,0};
__constant__ unsigned char JT0[NJOB] = { 0, 0, 0, 0, 0, 0, 0, 0, 0, 0, 0, 0, 0, 0, 0, 0, 0,16, 0,16, 0,16, 0,16, 0,16, 0,16, 0,16, 0,16, 0,16, 0,16, 0,16, 0,16, 0,16, 0, 0, 0};
__constant__ unsigned char JT1[NJOB] = {19,18,17,16,16,16,16,16,16,16,16,16,16,16,16,16,16,32,15,31,14,30,13,29,12,28,11,27,10,26, 9,25, 8,24, 7,23, 6,22, 5,21, 4,20, 3, 2, 1};

__device__ __forceinline__ int ktidx(int row, int ch) {
    return (((ch >> 3) << 3) + (row >> 3)) * 512 + (row & 7) * 64 + (((ch & 7) ^ (row & 7)) << 3);
}
// Vt: 16 groups of 8 d-rows; slot swizzle chunk^(d&7)
__device__ __forceinline__ int vtidx(int d, int ch) {
    return (d >> 3) * 512 + (d & 7) * 64 + ((ch ^ (d & 7)) << 3);
}

__launch_bounds__(256, 3)
__global__ void attn_mfma(const ushort* __restrict__ qbuf, const ushort* __restrict__ Kf,
                          const ushort* __restrict__ kvbf, const ushort* __restrict__ VT,
                          const int* __restrict__ mask, ushort* __restrict__ o_heads,
                          ushort* __restrict__ Opart, float2* __restrict__ mlbuf)
{
    __shared__ ushort Kt[24 * 512];      // 24,576 B shared K-tile (64 t x 192)
    __shared__ ushort Vt[16 * 512];      // 16,384 B shared V^T tile (128 d x 64 t)
    __shared__ ushort Pt[4 * 16 * PTL];  //  9,216 B wave-private P^T slabs

    const int tid = threadIdx.x, w = tid >> 6, lane = tid & 63;
    const int l15 = lane & 15, q = lane >> 4;
    const int r7 = lane >> 3, c7 = lane & 7;

    const int job = blockIdx.x >> 5, bh = blockIdx.x & 31;
    const int b = bh >> 4, h = bh & 15;
    const int qt = JQT[job], t0s = JT0[job], t1s = JT1[job];
    const int s0 = qt * 64;
    const bool partial = (t0s != 0) | (t1s != qt + 1);

    const ushort* Kf_bh = Kf + (size_t)bh * SS * NOPE_D;
    const ushort* VT_bh = VT + (size_t)bh * VD_D * SS;
    const ushort* kpe_b = kvbf + (size_t)b * SS * 576 + 512;
    const int* mrow = mask + b * SS;
    ushort* Ptw = Pt + w * 16 * PTL;

    // Q B-frags: rows s0+16w..+15 (n = lane&15), 6 k-chunks of 32 over 192 dims
    bf16x8 qf[6];
    {
        const ushort* qbase = qbuf + ((size_t)(b * SS) + s0 + 16 * w + l15) * 3072 + h * QKH_D + q * 8;
#pragma unroll
        for (int k = 0; k < 6; k++) qf[k] = *(const bf16x8*)(qbase + k * 32);
    }

    f32x4 Oacc[8];   // O^T: rows d = 16nt+4q+r, col s = l15
#pragma unroll
    for (int nt = 0; nt < 8; nt++) Oacc[nt] = (f32x4){0.f, 0.f, 0.f, 0.f};
    float m_i = -3e38f, l_i = 0.f;
    const int my_s = s0 + 16 * w + l15;

    for (int st = t0s; st < t1s; st++) {
        const int t0 = st * 64;
        // ---- stage K-tile (24 groups) + V^T tile (16 groups); wave w: 6 K + 4 V ----
#pragma unroll
        for (int i = 0; i < 6; i++) {
            int g = 6 * w + i;
            int rg = g & 7, cg = g >> 3;
            int row = rg * 8 + r7;
            int chl = c7 ^ r7;
            const ushort* src = (cg < 2)
                ? Kf_bh + (size_t)(t0 + row) * NOPE_D + (cg * 8 + chl) * 8
                : kpe_b + (size_t)(t0 + row) * 576 + chl * 8;
            gload_lds16(src, Kt + g * 512 + lane * 8);
        }
#pragma unroll
        for (int i = 0; i < 4; i++) {
            int g = 4 * w + i;                  // d-group 0..15
            int d = g * 8 + r7;
            gload_lds16(VT_bh + (size_t)d * SS + t0 + ((c7 ^ r7) << 3),
                        Vt + g * 512 + lane * 8);
        }
        __syncthreads();
        // ---- scores S^T(64 t x 16 s): sa[c] rows t=16c+4q+r, col s=l15 ----
        f32x4 sa[4];
#pragma unroll
        for (int c = 0; c < 4; c++) sa[c] = (f32x4){0.f, 0.f, 0.f, 0.f};
        __builtin_amdgcn_s_setprio(1);
#pragma unroll
        for (int k = 0; k < 6; k++) {
#pragma unroll
            for (int c = 0; c < 4; c++) {
                bf16x8 kb = *(const bf16x8*)(Kt + ktidx(16 * c + l15, 4 * k + q));
                sa[c] = __builtin_amdgcn_mfma_f32_16x16x32_bf16(kb, qf[k], sa[c], 0, 0, 0);
            }
        }
        __builtin_amdgcn_s_setprio(0);
        // ---- masked scores: causal only on the diagonal tile (st==qt) ----
        float sc[4][4];
        if (st == qt) {
#pragma unroll
            for (int c = 0; c < 4; c++) {
                int4 mv4 = *(const int4*)&mrow[t0 + 16 * c + 4 * q];
#pragma unroll
                for (int r = 0; r < 4; r++) {
                    int t = t0 + 16 * c + 4 * q + r;
                    float v = sa[c][r] * SCL;
                    if (t > my_s || (&mv4.x)[r] == 0) v = -1e30f;
                    sc[c][r] = v;
                }
            }
        } else {
#pragma unroll
            for (int c = 0; c < 4; c++) {
                int4 mv4 = *(const int4*)&mrow[t0 + 16 * c + 4 * q];
#pragma unroll
                for (int r = 0; r < 4; r++) {
                    float v = sa[c][r] * SCL;
                    if ((&mv4.x)[r] == 0) v = -1e30f;
                    sc[c][r] = v;
                }
            }
        }
        // ---- tree max (exact; fmax associative) + cross-quad reduce ----
        float mx = fmaxf(
            fmaxf(fmaxf(fmaxf(sc[0][0], sc[0][1]), fmaxf(sc[0][2], sc[0][3])),
                  fmaxf(fmaxf(sc[1][0], sc[1][1]), fmaxf(sc[1][2], sc[1][3]))),
            fmaxf(fmaxf(fmaxf(sc[2][0], sc[2][1]), fmaxf(sc[2][2], sc[2][3])),
                  fmaxf(fmaxf(sc[3][0], sc[3][1]), fmaxf(sc[3][2], sc[3][3]))));
        mx = fmaxf(mx, __shfl_xor(mx, 16));
        mx = fmaxf(mx, __shfl_xor(mx, 32));
        float mn = fmaxf(m_i, mx);
        // skip rescale when alpha==1 for ALL lanes (identity; THR=0, exact)
        if (!__all(mx <= m_i)) {
            float alpha = exp2f(m_i - mn);
            l_i *= alpha;
#pragma unroll
            for (int nt = 0; nt < 8; nt++) {
                Oacc[nt][0] *= alpha; Oacc[nt][1] *= alpha;
                Oacc[nt][2] *= alpha; Oacc[nt][3] *= alpha;
            }
        }
        m_i = mn;
        // ---- P = exp2(sc - mn); masked entries underflow to exactly 0 ----
        float ps = 0.f;
#pragma unroll
        for (int c = 0; c < 4; c++) {
            float p0 = exp2f(sc[c][0] - mn);
            float p1 = exp2f(sc[c][1] - mn);
            float p2 = exp2f(sc[c][2] - mn);
            float p3 = exp2f(sc[c][3] - mn);
            ps += (p0 + p1) + (p2 + p3);
            uint2 pk2;
            pk2.x = cvtpk(p0, p1);
            pk2.y = cvtpk(p2, p3);
            *(uint2*)(Ptw + l15 * PTL + 16 * c + 4 * q) = pk2;
        }
        ps += __shfl_xor(ps, 16);
        ps += __shfl_xor(ps, 32);
        l_i += ps;
        // ---- PV: O^T(128 d x 16 s) += V^T(LDS) @ P^T(wave LDS) ----
        bf16x8 pb[2];
#pragma unroll
        for (int kt = 0; kt < 2; kt++)
            pb[kt] = *(const bf16x8*)(Ptw + l15 * PTL + kt * 32 + q * 8);
        __builtin_amdgcn_s_setprio(1);
#pragma unroll
        for (int nt = 0; nt < 8; nt++) {
#pragma unroll
            for (int kt = 0; kt < 2; kt++) {
                bf16x8 vf = *(const bf16x8*)(Vt + vtidx(16 * nt + l15, kt * 4 + q));
                Oacc[nt] = __builtin_amdgcn_mfma_f32_16x16x32_bf16(vf, pb[kt], Oacc[nt], 0, 0, 0);
            }
        }
        __builtin_amdgcn_s_setprio(0);
        __syncthreads();   // protect Kt/Vt for next step
    }

    // ---- epilogue (intra-wave; O^T rows d = 16nt+4q+r, col s = l15) ----
    float lv = (l_i > 0.f) ? 1.f / l_i : 0.f;

    if (!partial) {
        ushort* orow = o_heads + (size_t)(b * SS + my_s) * 2048 + h * VD_D;
#pragma unroll
        for (int nt = 0; nt < 8; nt++) {
            ushort4 pk;
            pk.x = f2bf(Oacc[nt][0] * lv); pk.y = f2bf(Oacc[nt][1] * lv);
            pk.z = f2bf(Oacc[nt][2] * lv); pk.w = f2bf(Oacc[nt][3] * lv);
            *(ushort4*)(orow + 16 * nt + 4 * q) = pk;
        }
    } else {
        const int sp = (t0s != 0);
        const int p = bh * 26 + (qt - 19) * 2 + sp;
        const int rl = 16 * w + l15;
        ushort* prow = Opart + ((size_t)p * 64 + rl) * 128;
#pragma unroll
        for (int nt = 0; nt < 8; nt++) {
            ushort4 pk;
            pk.x = f2bf(Oacc[nt][0] * lv); pk.y = f2bf(Oacc[nt][1] * lv);
            pk.z = f2bf(Oacc[nt][2] * lv); pk.w = f2bf(Oacc[nt][3] * lv);
            *(ushort4*)(prow + 16 * nt + 4 * q) = pk;
        }
        if (lane < 16)
            mlbuf[p * 64 + rl] = make_float2(m_i, l_i);
    }
}

// ---------------------------------------------------------------------------
// Merge span0/span1 partials for qt>=19.  grid 416 (= 32bh x 13qt) x 256.
// ---------------------------------------------------------------------------
__launch_bounds__(256)
__global__ void attn_merge(const ushort* __restrict__ Opart, const float2* __restrict__ mlbuf,
                           ushort* __restrict__ o_heads)
{
    int bh = blockIdx.x & 31, qi = blockIdx.x >> 5;
    int b = bh >> 4, h = bh & 15;
    int qt = 19 + qi;
    int t = threadIdx.x;
    int row = t >> 2, dbase = (t & 3) * 32;
    int p0 = bh * 26 + qi * 2, p1 = p0 + 1;
    float2 ml0 = mlbuf[p0 * 64 + row], ml1 = mlbuf[p1 * 64 + row];
    float M = fmaxf(ml0.x, ml1.x);
    float w0 = (ml0.y > 0.f) ? exp2f(ml0.x - M) * ml0.y : 0.f;
    float w1 = (ml1.y > 0.f) ? exp2f(ml1.x - M) * ml1.y : 0.f;
    float den = w0 + w1;
    float inv = (den > 0.f) ? 1.f / den : 0.f;
    w0 *= inv; w1 *= inv;
    int s = qt * 64 + row;
    const ushort* O0 = Opart + ((size_t)p0 * 64 + row) * 128 + dbase;
    const ushort* O1 = Opart + ((size_t)p1 * 64 + row) * 128 + dbase;
    ushort* dst = o_heads + (size_t)(b * SS + s) * 2048 + h * VD_D + dbase;
#pragma unroll
    for (int c = 0; c < 32; c += 8) {
        bf16x8 a = *(const bf16x8*)(O0 + c);
        bf16x8 bb = *(const bf16x8*)(O1 + c);
        bf16x8 o;
#pragma unroll
        for (int j = 0; j < 8; j++)
            o[j] = (short)f2bf(w0 * bf2f((unsigned short)a[j]) + w1 * bf2f((unsigned short)bb[j]));
        *(bf16x8*)(dst + c) = o;
    }
}

extern "C" void kernel_launch(void* const* d_in, const int* in_sizes, int n_in,
                              void* d_out, int out_size, void* d_ws, size_t ws_size,
                              hipStream_t stream)
{
    const float* x        = (const float*)d_in[0];
    const int*   mask     = (const int*)d_in[1];
    const float* wq_a_w   = (const float*)d_in[2];
    const float* wq_a_b   = (const float*)d_in[3];
    const float* q_norm_w = (const float*)d_in[4];
    const float* wq_b_w   = (const float*)d_in[5];
    const float* wq_b_b   = (const float*)d_in[6];
    const float* wkv_a_w  = (const float*)d_in[7];
    const float* wkv_a_b  = (const float*)d_in[8];
    const float* kv_norm_w= (const float*)d_in[9];
    const float* wkv_b_w  = (const float*)d_in[10];
    const float* wo_w     = (const float*)d_in[11];
    const float* wo_b     = (const float*)d_in[12];
    float* out = (float*)d_out;

    // Workspace — peak 102,662,144 B (step-10 packing unchanged from R0).
    // Lifetimes: x_bf w0 r1 | wqkv_a w0 r1 | cbias w0 r1 | qkv_a w1 r2,3,5 |
    //   wq_b w0 r3 | qbuf w3 r6,10 | kvbf w5 r7,9,10 | wkv_b w0 r7,9 |
    //   Kf w7 r10 | VT w9 r10 | o_heads w10/11 r12 | Opart/mlbuf w10 r11.
    char* W = (char*)d_ws;
    ushort* wo_bf    = (ushort*)(W + 0);           // 8,388,608   (whole run)
    ushort* x_bf     = (ushort*)(W + 8388608);     // 16.8M, dead after step 1
    ushort* qbuf     = (ushort*)(W + 8388608);     // 25.2M, w3 (after x dead)
    ushort* wq_b_bf  = (ushort*)(W + 33554432);    // 9.4M, r3
    ushort* Kf       = (ushort*)(W + 33554432);    // 16.8M, w7 (after r3)
    ushort* wqkv_a_bf= (ushort*)(W + 42991616);    // 8.65M, r1 (in Kf/VT holes)
    float*  cbias    = (float*) (W + 51642368);    // 8.4K, r1 (VT hole)
    ushort* VT       = (ushort*)(W + 50331648);    // 16.8M, w9
    ushort* qkv_a    = (ushort*)(W + 67108864);    // 17.3M, w1 r2,3,5
    ushort* o_heads  = (ushort*)(W + 67108864);    // 16.8M, w10 (after r5)
    ushort* Opart    = (ushort*)(W + 83886080);    // 13.6M, w10
    ushort* wkv_b_bf = (ushort*)(W + 84410368);    // 4.2M, r7,9 (Opart hole,
                                                   //  clear of qkv_a tail)
    float2* mlbuf    = (float2*)(W + 97517568);
    ushort* kvbf     = (ushort*)(W + 97943552);

    // 0. all f32->bf16 converts + combined [wq_a;wkv_a] weight + bias
    conv6<<<4096, 256, 0, stream>>>(
        x, x_bf, MROWS * HH / 4,
        wq_a_w, wqkv_a_bf, QLL * HH / 4,
        wkv_a_w, wqkv_a_bf + (size_t)QLL * HH, 576 * HH / 4,
        wq_b_w, wq_b_bf, 3072 * QLL / 4,
        wkv_b_w, wkv_b_bf, NHH * 256 * 512 / 4,
        wo_w, wo_bf, HH * 2048 / 4,
        wq_a_b, wkv_a_b, cbias);

    // 1. qkv_a = x @ [wq_a; wkv_a]^T + [b;b]  (merged; N=2112 guarded)
    gemm_bf<ushort><<<dim3(17, MROWS/128, 1), 256, 0, stream>>>(
        x_bf, HH, 0, 0, wqkv_a_bf, HH, 0, 0, cbias, qkv_a, NQKV, 0, 0,
        MROWS, NQKV, HH);
    // 2. rms_norm q-latent in place (cols 0..1535, stride 2112)
    rmsnorm_bf16<<<MROWS, 256, 0, stream>>>(qkv_a, q_norm_w, QLL, NQKV);
    // 3. q = q_a @ wq_b^T + b -> qbuf bf16  (A = qkv_a q-part, lda 2112)
    gemm_bf<ushort><<<dim3(3072/128, MROWS/128, 1), 256, 0, stream>>>(
        qkv_a, NQKV, 0, 0, wq_b_bf, QLL, 0, 0, wq_b_b, qbuf, 3072, 0, 0,
        MROWS, 3072, QLL);
    // 5. finalize kv (rms + rope) from qkv_a kv-part -> kvbf
    finalize_kv<<<MROWS, 256, 0, stream>>>(qkv_a, kv_norm_w, kvbf);
    // 6. rope q_pe in place on qbuf
    rope_q_kernel<<<dim3(MROWS, 4), 256, 0, stream>>>(qbuf);
    // 7. Kf[b,h] = kv_lat @ W_UK[h]^T  (nope only; M=2048,N=128,K=512, z=32)
    gemm_bf<ushort><<<dim3(1, SS/128, 32), 256, 0, stream>>>(
        kvbf, 576, (size_t)SS * 576, 0,
        wkv_b_bf, 512, 0, (size_t)256 * 512,
        nullptr, Kf, NOPE_D, (size_t)NHH * SS * NOPE_D, (size_t)SS * NOPE_D,
        SS, NOPE_D, 512);
    // 9. VT[b,h] = W_UV[h] @ kv_lat^T  (M=128,N=2048,K=512, z=32)
    gemm_bf<ushort><<<dim3(SS/128, 1, 32), 256, 0, stream>>>(
        wkv_b_bf + (size_t)128 * 512, 512, 0, (size_t)256 * 512,
        kvbf, 576, (size_t)SS * 576, 0,
        nullptr, VT, SS, (size_t)NHH * VD_D * SS, (size_t)VD_D * SS,
        VD_D, SS, 512);
    // 10. split-K MFMA flash attention (1440 blocks) + merge
    attn_mfma<<<NJOB * 32, 256, 0, stream>>>(qbuf, Kf, kvbf, VT, mask, o_heads, Opart, mlbuf);
    attn_merge<<<13 * 32, 256, 0, stream>>>(Opart, mlbuf, o_heads);
    // 12. out = o_heads @ wo^T + b
    gemm_bf<float><<<dim3(HH/128, MROWS/128, 1), 256, 0, stream>>>(
        o_heads, NHH * VD_D, 0, 0, wo_bf, NHH * VD_D, 0, 0, wo_b, out, HH, 0, 0,
        MROWS, HH, NHH * VD_D);
}